// Round 1
// baseline (1519.893 us; speedup 1.0000x reference)
//
#include <hip/hip_runtime.h>
#include <math.h>

#define EPSF 1e-5f

__device__ __forceinline__ float wred64(float v){
  #pragma unroll
  for (int m = 1; m < 64; m <<= 1) v += __shfl_xor(v, m, 64);
  return v;
}
__device__ __forceinline__ float wred16(float v){
  #pragma unroll
  for (int m = 1; m < 16; m <<= 1) v += __shfl_xor(v, m, 64);
  return v;
}

// ---- weight transpose: w[CO][CINK] -> wt[CINK][CO] (so conv weight reads are
// block-uniform *contiguous* -> s_load_dwordx16)
__global__ __launch_bounds__(256) void wtrans_k(const float* __restrict__ w, float* __restrict__ wt,
                                                int CO, int CINK){
  int idx = blockIdx.x * 256 + threadIdx.x;
  if (idx >= CO * CINK) return;
  int co = idx % CO, rk = idx / CO;
  wt[idx] = w[co * CINK + rk];
}

// ---- conv1: x(256,3,64,64) k5 s2 p2 -> (256,64,32,32), fused IN+lrelu.
// block=256 per (n, 4-co group); 4 px/thread; all 3 cin planes staged padded in LDS.
__global__ __launch_bounds__(256) void conv1_k(const float* __restrict__ x, const float* __restrict__ wt,
                                               const float* __restrict__ g, const float* __restrict__ be,
                                               float* __restrict__ out){
  const int t = threadIdx.x;
  const int n = blockIdx.y;
  const int co0 = blockIdx.x * 4;
  __shared__ float plane[3][68*72];   // rows: ih+2 (0..67), cols: iw+4 (left pad 4 for f4 align)
  __shared__ float redS[16], redQ[16];
  float* pl = (float*)plane;
  for (int k = t; k < 3*68*72; k += 256) pl[k] = 0.f;
  __syncthreads();
  for (int f4 = t; f4 < 3*1024; f4 += 256){
    int ci = f4 >> 10, rem = f4 & 1023;
    int ih = rem >> 4, iw4 = (rem & 15) << 2;
    float4 v = *(const float4*)&x[((n*3 + ci) << 12) + (ih << 6) + iw4];
    *(float4*)&plane[ci][(ih+2)*72 + iw4 + 4] = v;
  }
  __syncthreads();
  float acc[4][4] = {};
  int base[4];
  #pragma unroll
  for (int m = 0; m < 4; m++){
    int px = t + (m << 8);
    int oh = px >> 5, ow = px & 31;
    base[m] = (oh*2)*72 + ow*2 + 2;   // ih_eff=oh*2+kh, iw_eff=ow*2+kw+2
  }
  #pragma unroll
  for (int ci = 0; ci < 3; ci++){
    const float* P = plane[ci];
    const float* W = wt + ci*25*64 + co0;
    #pragma unroll
    for (int kh = 0; kh < 5; kh++){
      #pragma unroll
      for (int kw = 0; kw < 5; kw++){
        const float* Wp = W + (kh*5+kw)*64;
        float w0 = Wp[0], w1 = Wp[1], w2 = Wp[2], w3 = Wp[3];
        #pragma unroll
        for (int m = 0; m < 4; m++){
          float v = P[base[m] + kh*72 + kw];
          acc[m][0] += v*w0; acc[m][1] += v*w1; acc[m][2] += v*w2; acc[m][3] += v*w3;
        }
      }
    }
  }
  int wid = t >> 6;
  #pragma unroll
  for (int c = 0; c < 4; c++){
    float s = acc[0][c]+acc[1][c]+acc[2][c]+acc[3][c];
    float q = acc[0][c]*acc[0][c]+acc[1][c]*acc[1][c]+acc[2][c]*acc[2][c]+acc[3][c]*acc[3][c];
    s = wred64(s); q = wred64(q);
    if ((t & 63) == 0){ redS[wid*4+c] = s; redQ[wid*4+c] = q; }
  }
  __syncthreads();
  #pragma unroll
  for (int c = 0; c < 4; c++){
    float S = redS[c] + redS[4+c] + redS[8+c] + redS[12+c];
    float Q = redQ[c] + redQ[4+c] + redQ[8+c] + redQ[12+c];
    float mu = S * (1.f/1024.f);
    float var = Q * (1.f/1024.f) - mu*mu;
    float gm = g[co0+c] * rsqrtf(var + EPSF), bt = be[co0+c];
    #pragma unroll
    for (int m = 0; m < 4; m++){
      int px = t + (m << 8);
      float v = (acc[m][c] - mu) * gm + bt;
      v = v >= 0.f ? v : 0.2f*v;
      out[((n*64 + co0 + c) << 10) + px] = v;
    }
  }
}

// ---- conv2: (256,64,32,32) k5 s2 p2 -> (256,128,16,16). COG=16/thread, 4-cin chunks.
__global__ __launch_bounds__(256) void conv2_k(const float* __restrict__ in, const float* __restrict__ wt,
                                               const float* __restrict__ g, const float* __restrict__ be,
                                               float* __restrict__ out){
  const int t = threadIdx.x;
  const int n = blockIdx.y;
  const int co0 = blockIdx.x << 4;
  __shared__ float plane[4][36*40];
  __shared__ float redS[64], redQ[64];
  float* pl = (float*)plane;
  for (int k = t; k < 4*36*40; k += 256) pl[k] = 0.f;
  __syncthreads();
  const int oh = t >> 4, ow = t & 15;
  const int base = (oh*2)*40 + ow*2 + 2;
  float acc[16] = {};
  for (int c0 = 0; c0 < 64; c0 += 4){
    #pragma unroll
    for (int m = 0; m < 4; m++){
      int f4 = t + (m << 8);
      int ci = f4 >> 8, rem = f4 & 255;
      int ih = rem >> 3, iw4 = (rem & 7) << 2;
      float4 v = *(const float4*)&in[((n*64 + c0 + ci) << 10) + (ih << 5) + iw4];
      *(float4*)&plane[ci][(ih+2)*40 + iw4 + 4] = v;
    }
    __syncthreads();
    #pragma unroll
    for (int ci = 0; ci < 4; ci++){
      const float* P = plane[ci] + base;
      const float* W = wt + (c0+ci)*25*128 + co0;
      #pragma unroll
      for (int kh = 0; kh < 5; kh++){
        #pragma unroll
        for (int kw = 0; kw < 5; kw++){
          float v = P[kh*40 + kw];
          const float* Wp = W + (kh*5+kw)*128;
          #pragma unroll
          for (int c = 0; c < 16; c++) acc[c] += v * Wp[c];
        }
      }
    }
    __syncthreads();
  }
  int wid = t >> 6;
  #pragma unroll
  for (int c = 0; c < 16; c++){
    float a = acc[c];
    float s = wred64(a), q = wred64(a*a);
    if ((t & 63) == 0){ redS[wid*16+c] = s; redQ[wid*16+c] = q; }
  }
  __syncthreads();
  #pragma unroll
  for (int c = 0; c < 16; c++){
    float S = redS[c]+redS[16+c]+redS[32+c]+redS[48+c];
    float Q = redQ[c]+redQ[16+c]+redQ[32+c]+redQ[48+c];
    float mu = S*(1.f/256.f), var = Q*(1.f/256.f) - mu*mu;
    float v = (acc[c]-mu)*rsqrtf(var + EPSF)*g[co0+c] + be[co0+c];
    v = v >= 0.f ? v : 0.2f*v;
    out[((n*128 + co0 + c) << 8) + t] = v;
  }
}

// ---- conv3: (256,128,16,16) k5 s2 p2 -> (256,256,8,8). block: 4 n_sub x 64 px; COG=16.
__global__ __launch_bounds__(256) void conv3_k(const float* __restrict__ in, const float* __restrict__ wt,
                                               const float* __restrict__ g, const float* __restrict__ be,
                                               float* __restrict__ out){
  const int t = threadIdx.x;
  const int n0 = blockIdx.y << 2;
  const int co0 = blockIdx.x << 4;
  __shared__ float plane[4][4][20*24];
  float* pl = (float*)plane;
  for (int k = t; k < 4*4*480; k += 256) pl[k] = 0.f;
  __syncthreads();
  const int ns = t >> 6, px = t & 63;
  const int oh = px >> 3, ow = px & 7;
  const int base = (oh*2)*24 + ow*2 + 2;
  float acc[16] = {};
  for (int c0 = 0; c0 < 128; c0 += 4){
    #pragma unroll
    for (int m = 0; m < 4; m++){
      int f4 = t + (m << 8);
      int ci = f4 >> 8, rem = f4 & 255;
      int nl = rem >> 6, cell4 = (rem & 63) << 2;
      int ih = cell4 >> 4, iw4 = cell4 & 15;
      float4 v = *(const float4*)&in[(((n0+nl)*128 + c0 + ci) << 8) + cell4];
      *(float4*)&plane[ci][nl][(ih+2)*24 + iw4 + 4] = v;
    }
    __syncthreads();
    #pragma unroll
    for (int ci = 0; ci < 4; ci++){
      const float* P = plane[ci][ns] + base;
      const float* W = wt + (c0+ci)*25*256 + co0;
      #pragma unroll
      for (int kh = 0; kh < 5; kh++){
        #pragma unroll
        for (int kw = 0; kw < 5; kw++){
          float v = P[kh*24 + kw];
          const float* Wp = W + (kh*5+kw)*256;
          #pragma unroll
          for (int c = 0; c < 16; c++) acc[c] += v * Wp[c];
        }
      }
    }
    __syncthreads();
  }
  #pragma unroll
  for (int c = 0; c < 16; c++){
    float a = acc[c];
    float s = wred64(a), q = wred64(a*a);   // each co-plane lives entirely in this wave
    float mu = s*(1.f/64.f), var = q*(1.f/64.f) - mu*mu;
    float v = (a-mu)*rsqrtf(var + EPSF)*g[co0+c] + be[co0+c];
    v = v >= 0.f ? v : 0.2f*v;
    out[(((n0+ns)*256 + co0 + c) << 6) + px] = v;
  }
}

// ---- conv4: (256,256,8,8) k3 s2 p1 -> feat (d_out). block: 16 n_sub x 16 px; COG=16.
__global__ __launch_bounds__(256) void conv4_k(const float* __restrict__ in, const float* __restrict__ wt,
                                               const float* __restrict__ g, const float* __restrict__ be,
                                               float* __restrict__ out){
  const int t = threadIdx.x;
  const int n0 = blockIdx.y << 4;
  const int co0 = blockIdx.x << 4;
  __shared__ float plane[4][16][120];   // rows ih+1 (0..9), cols iw+4 (left pad 4)
  float* pl = (float*)plane;
  for (int k = t; k < 4*16*120; k += 256) pl[k] = 0.f;
  __syncthreads();
  const int ns = t >> 4, px = t & 15;
  const int oh = px >> 2, ow = px & 3;
  const int base = (oh*2)*12 + ow*2 + 3;  // iw_eff = ow*2 - 1 + kw + 4
  float acc[16] = {};
  for (int c0 = 0; c0 < 256; c0 += 4){
    #pragma unroll
    for (int m = 0; m < 4; m++){
      int f4 = t + (m << 8);
      int ci = f4 >> 8, rem = f4 & 255;
      int nl = rem >> 4, cell4 = (rem & 15) << 2;
      int ih = cell4 >> 3, iw4 = cell4 & 7;
      float4 v = *(const float4*)&in[(((n0+nl)*256 + c0 + ci) << 6) + cell4];
      *(float4*)&plane[ci][nl][(ih+1)*12 + iw4 + 4] = v;
    }
    __syncthreads();
    #pragma unroll
    for (int ci = 0; ci < 4; ci++){
      const float* P = plane[ci][ns] + base;
      const float* W = wt + (c0+ci)*9*256 + co0;
      #pragma unroll
      for (int kh = 0; kh < 3; kh++){
        #pragma unroll
        for (int kw = 0; kw < 3; kw++){
          float v = P[kh*12 + kw];
          const float* Wp = W + (kh*3+kw)*256;
          #pragma unroll
          for (int c = 0; c < 16; c++) acc[c] += v * Wp[c];
        }
      }
    }
    __syncthreads();
  }
  #pragma unroll
  for (int c = 0; c < 16; c++){
    float a = acc[c];
    float s = wred16(a), q = wred16(a*a);   // 16-lane segment = this (n,co) plane
    float mu = s*(1.f/16.f), var = q*(1.f/16.f) - mu*mu;
    float v = (a-mu)*rsqrtf(var + EPSF)*g[co0+c] + be[co0+c];
    v = v >= 0.f ? v : 0.2f*v;
    out[(n0+ns)*4096 + ((co0+c) << 4) + px] = v;
  }
}

// ---- M einsum: Cp[z] = feat(256x4096) @ T(4096x3200), K split 8x512. 128x128 tile, 8x8 micro.
__global__ __launch_bounds__(256) void gemmM_k(const float* __restrict__ A, const float* __restrict__ B,
                                               float* __restrict__ Cp){
  const int t = threadIdx.x;
  const int on0 = blockIdx.x << 7;
  const int b0 = blockIdx.y << 7;
  const int k0 = blockIdx.z << 9;
  __shared__ float Asm[32][132];   // [k][b] transposed
  __shared__ float Bsm[32][132];   // [k][n]
  const int tx = t & 15, ty = t >> 4;
  float acc[8][8] = {};
  for (int kk = 0; kk < 512; kk += 32){
    #pragma unroll
    for (int m = 0; m < 4; m++){
      int f4 = t + (m << 8);
      int b = f4 >> 3, seg = f4 & 7;
      float4 v = *(const float4*)&A[((b0 + b) << 12) + k0 + kk + (seg << 2)];
      Asm[(seg<<2)+0][b] = v.x; Asm[(seg<<2)+1][b] = v.y; Asm[(seg<<2)+2][b] = v.z; Asm[(seg<<2)+3][b] = v.w;
    }
    #pragma unroll
    for (int m = 0; m < 4; m++){
      int f4 = t + (m << 8);
      int ii = f4 >> 5, seg = f4 & 31;
      float4 v = *(const float4*)&B[(k0 + kk + ii)*3200 + on0 + (seg << 2)];
      *(float4*)&Bsm[ii][seg << 2] = v;
    }
    __syncthreads();
    #pragma unroll
    for (int ii = 0; ii < 32; ii++){
      float4 a0 = *(const float4*)&Asm[ii][ty << 3];
      float4 a1 = *(const float4*)&Asm[ii][(ty << 3) + 4];
      float4 c0v = *(const float4*)&Bsm[ii][tx << 3];
      float4 c1v = *(const float4*)&Bsm[ii][(tx << 3) + 4];
      float av[8] = {a0.x,a0.y,a0.z,a0.w,a1.x,a1.y,a1.z,a1.w};
      float bw[8] = {c0v.x,c0v.y,c0v.z,c0v.w,c1v.x,c1v.y,c1v.z,c1v.w};
      #pragma unroll
      for (int p = 0; p < 8; p++)
        #pragma unroll
        for (int q = 0; q < 8; q++) acc[p][q] += av[p]*bw[q];
    }
    __syncthreads();
  }
  float* C = Cp + blockIdx.z * 819200;
  #pragma unroll
  for (int p = 0; p < 8; p++){
    int row = b0 + (ty << 3) + p;
    float4 v0 = {acc[p][0],acc[p][1],acc[p][2],acc[p][3]};
    float4 v1 = {acc[p][4],acc[p][5],acc[p][6],acc[p][7]};
    *(float4*)&C[row*3200 + on0 + (tx << 3)] = v0;
    *(float4*)&C[row*3200 + on0 + (tx << 3) + 4] = v1;
  }
}

__global__ __launch_bounds__(256) void reduceM_k(const float* __restrict__ Cp, float* __restrict__ M){
  int i4 = blockIdx.x * 256 + threadIdx.x;
  if (i4 >= 204800) return;
  float4 r = {0,0,0,0};
  #pragma unroll
  for (int s = 0; s < 8; s++){
    float4 v = *(const float4*)&Cp[s*819200 + (i4 << 2)];
    r.x += v.x; r.y += v.y; r.z += v.z; r.w += v.w;
  }
  *(float4*)&M[i4 << 2] = r;
}

// ---- pairwise: o_b[j,o] = sum_i exp(-sum_k |M[i,o,k]-M[j,o,k]|) - 1
__global__ __launch_bounds__(256) void pair_k(const float* __restrict__ M, float* __restrict__ ob){
  const int j = blockIdx.x, t = threadIdx.x;
  __shared__ float Mj[3200];
  __shared__ float red[256];
  for (int k = t; k < 3200; k += 256) Mj[k] = M[j*3200 + k];
  __syncthreads();
  const int o = t & 63, ss = t >> 6;
  const float2* mj = (const float2*)&Mj[o*50];
  float sum = 0.f;
  for (int i = ss << 6; i < (ss << 6) + 64; i++){
    const float2* mi = (const float2*)&M[i*3200 + o*50];
    float d = 0.f;
    #pragma unroll
    for (int k2 = 0; k2 < 25; k2++){
      float2 a = mi[k2], b = mj[k2];
      d += fabsf(a.x - b.x) + fabsf(a.y - b.y);
    }
    sum += expf(-d);
  }
  red[(o << 2) + ss] = sum;
  __syncthreads();
  if (t < 64) ob[(j << 6) + t] = red[t<<2] + red[(t<<2)+1] + red[(t<<2)+2] + red[(t<<2)+3] - 1.0f;
}

// ---- fc: ypart[z] = mb(256x4160) @ fc_w(1000x4160)^T tile, K split 13x320.
__global__ __launch_bounds__(256) void gemmFC_k(const float* __restrict__ feat, const float* __restrict__ ob,
                                                const float* __restrict__ W, float* __restrict__ Cp){
  const int t = threadIdx.x;
  const int o0 = blockIdx.x << 7;
  const int b0 = blockIdx.y << 7;
  const int k0 = blockIdx.z * 320;
  __shared__ float Asm[32][132];
  __shared__ float Bsm[32][132];
  const int tx = t & 15, ty = t >> 4;
  float acc[8][8] = {};
  for (int kk = 0; kk < 320; kk += 32){
    #pragma unroll
    for (int m = 0; m < 4; m++){
      int f4 = t + (m << 8);
      int b = f4 >> 3, seg = f4 & 7;
      int i = k0 + kk + (seg << 2);
      float4 v;
      if (i < 4096) v = *(const float4*)&feat[((b0 + b) << 12) + i];
      else          v = *(const float4*)&ob[((b0 + b) << 6) + (i - 4096)];
      Asm[(seg<<2)+0][b] = v.x; Asm[(seg<<2)+1][b] = v.y; Asm[(seg<<2)+2][b] = v.z; Asm[(seg<<2)+3][b] = v.w;
    }
    #pragma unroll
    for (int m = 0; m < 4; m++){
      int f4 = t + (m << 8);
      int oo = f4 >> 3, seg = f4 & 7;
      float4 v = {0,0,0,0};
      if (o0 + oo < 1000) v = *(const float4*)&W[(o0 + oo)*4160 + k0 + kk + (seg << 2)];
      Bsm[(seg<<2)+0][oo] = v.x; Bsm[(seg<<2)+1][oo] = v.y; Bsm[(seg<<2)+2][oo] = v.z; Bsm[(seg<<2)+3][oo] = v.w;
    }
    __syncthreads();
    #pragma unroll
    for (int ii = 0; ii < 32; ii++){
      float4 a0 = *(const float4*)&Asm[ii][ty << 3];
      float4 a1 = *(const float4*)&Asm[ii][(ty << 3) + 4];
      float4 c0v = *(const float4*)&Bsm[ii][tx << 3];
      float4 c1v = *(const float4*)&Bsm[ii][(tx << 3) + 4];
      float av[8] = {a0.x,a0.y,a0.z,a0.w,a1.x,a1.y,a1.z,a1.w};
      float bw[8] = {c0v.x,c0v.y,c0v.z,c0v.w,c1v.x,c1v.y,c1v.z,c1v.w};
      #pragma unroll
      for (int p = 0; p < 8; p++)
        #pragma unroll
        for (int q = 0; q < 8; q++) acc[p][q] += av[p]*bw[q];
    }
    __syncthreads();
  }
  float* C = Cp + blockIdx.z * 256000;
  #pragma unroll
  for (int p = 0; p < 8; p++){
    int row = b0 + (ty << 3) + p;
    #pragma unroll
    for (int q = 0; q < 8; q++){
      int o = o0 + (tx << 3) + q;
      if (o < 1000) C[row*1000 + o] = acc[p][q];
    }
  }
}

__global__ __launch_bounds__(256) void reduceY_k(const float* __restrict__ Cp, const float* __restrict__ bias,
                                                 float* __restrict__ y){
  int idx = blockIdx.x * 256 + threadIdx.x;
  if (idx >= 256000) return;
  int o = idx % 1000;
  float r = bias[o];
  #pragma unroll
  for (int s = 0; s < 13; s++) r += Cp[s*256000 + idx];
  y[idx] = r;
}

extern "C" void kernel_launch(void* const* d_in, const int* in_sizes, int n_in,
                              void* d_out, int out_size, void* d_ws, size_t ws_size,
                              hipStream_t stream){
  const float* x   = (const float*)d_in[0];
  const float* w1  = (const float*)d_in[1];
  const float* g1  = (const float*)d_in[3];
  const float* be1 = (const float*)d_in[4];
  const float* w2  = (const float*)d_in[5];
  const float* g2  = (const float*)d_in[7];
  const float* be2 = (const float*)d_in[8];
  const float* w3  = (const float*)d_in[9];
  const float* g3  = (const float*)d_in[11];
  const float* be3 = (const float*)d_in[12];
  const float* w4  = (const float*)d_in[13];
  const float* g4  = (const float*)d_in[15];
  const float* be4 = (const float*)d_in[16];
  const float* T   = (const float*)d_in[17];
  const float* fcw = (const float*)d_in[18];
  const float* fcb = (const float*)d_in[19];
  float* out = (float*)d_out;
  float* ws  = (float*)d_ws;

  // workspace layout (floats); f3/M/o_b/partials alias the dead f1 region
  float* f1   = ws;                    // 16,777,216
  float* f2   = ws + 16777216;         //  8,388,608
  float* wt1  = ws + 25165824;         //      4,800
  float* wt2  = ws + 25170624;         //    204,800
  float* wt3  = ws + 25375424;         //    819,200
  float* wt4  = ws + 26194624;         //    589,824  (end: 26,784,448 floats = 107 MB)
  float* f3   = ws;                    //  4,194,304 (alias f1)
  float* Mb   = ws + 4194304;          //    819,200
  float* obuf = ws + 5013504;          //     16,384
  float* Mp   = ws + 5029888;          //  6,553,600
  float* yp   = ws + 11583488;         //  3,328,000
  float* feat = out;                   // d_out[0 .. 1048575]
  float* y    = out + 1048576;         // d_out[1048576 .. 1304575]

  wtrans_k<<<dim3(19),   256, 0, stream>>>(w1, wt1, 64, 75);
  wtrans_k<<<dim3(800),  256, 0, stream>>>(w2, wt2, 128, 1600);
  wtrans_k<<<dim3(3200), 256, 0, stream>>>(w3, wt3, 256, 3200);
  wtrans_k<<<dim3(2304), 256, 0, stream>>>(w4, wt4, 256, 2304);

  conv1_k<<<dim3(16, 256), 256, 0, stream>>>(x,  wt1, g1, be1, f1);
  conv2_k<<<dim3(8,  256), 256, 0, stream>>>(f1, wt2, g2, be2, f2);
  conv3_k<<<dim3(16, 64),  256, 0, stream>>>(f2, wt3, g3, be3, f3);
  conv4_k<<<dim3(16, 16),  256, 0, stream>>>(f3, wt4, g4, be4, feat);

  gemmM_k<<<dim3(25, 2, 8), 256, 0, stream>>>(feat, T, Mp);
  reduceM_k<<<dim3(800), 256, 0, stream>>>(Mp, Mb);
  pair_k<<<dim3(256), 256, 0, stream>>>(Mb, obuf);
  gemmFC_k<<<dim3(8, 2, 13), 256, 0, stream>>>(feat, obuf, fcw, yp);
  reduceY_k<<<dim3(1000), 256, 0, stream>>>(yp, fcb, y);
}

// Round 2
// 857.725 us; speedup vs baseline: 1.7720x; 1.7720x over previous
//
#include <hip/hip_runtime.h>
#include <math.h>

#define EPSF 1e-5f

typedef __attribute__((ext_vector_type(4))) float  floatx4;
typedef __attribute__((ext_vector_type(4))) short  short4v;
typedef __attribute__((ext_vector_type(8))) short  short8v;

__device__ __forceinline__ float wred64(float v){
  #pragma unroll
  for (int m = 1; m < 64; m <<= 1) v += __shfl_xor(v, m, 64);
  return v;
}
__device__ __forceinline__ unsigned short cvt_bf16(float f){
  unsigned u = __float_as_uint(f);
  unsigned r = (u + 0x7FFFu + ((u >> 16) & 1u)) >> 16;
  return (unsigned short)r;
}
__device__ __forceinline__ float bf2f(unsigned short h){
  return __uint_as_float(((unsigned)h) << 16);
}
__device__ __forceinline__ short8v ld_frag(const unsigned short* p){
  short4v lo = *(const short4v*)p;
  short4v hi = *(const short4v*)(p + 4);
  return __builtin_shufflevector(lo, hi, 0,1,2,3,4,5,6,7);
}
__device__ __forceinline__ float lrelu(float x){ return x >= 0.f ? x : 0.2f*x; }

__global__ __launch_bounds__(256) void zero_k(float* __restrict__ p, int n){
  int i = blockIdx.x*256 + threadIdx.x;
  if (i < n) p[i] = 0.f;
}

// conv1 weights: w[co][cin*25] -> wt[k][co] fp32 (block-uniform contiguous reads)
__global__ __launch_bounds__(256) void wtrans_k(const float* __restrict__ w, float* __restrict__ wt,
                                                int CO, int CINK){
  int idx = blockIdx.x * 256 + threadIdx.x;
  if (idx >= CO * CINK) return;
  int co = idx % CO, rk = idx / CO;
  wt[idx] = w[co * CINK + rk];
}

// MFMA conv weights: w[co][ci][tap] fp32 -> wb[co][tap][ci] bf16
__global__ __launch_bounds__(256) void wprep_k(const float* __restrict__ w, unsigned short* __restrict__ wb,
                                               int CO, int CIN, int TAPS){
  int idx = blockIdx.x*256 + threadIdx.x;
  int tc = CIN*TAPS;
  if (idx >= CO*tc) return;
  int co = idx / tc, r = idx - co*tc;
  int tap = r / CIN, ci = r - tap*CIN;
  wb[idx] = cvt_bf16(w[(co*CIN + ci)*TAPS + tap]);
}

// ---- conv1: x(256,3,64,64) fp32 NCHW, k5 s2 p2 -> f1 NHWC bf16 (256,32,32,64), fused IN+lrelu
__global__ __launch_bounds__(256) void conv1_k(const float* __restrict__ x, const float* __restrict__ wt,
                                               const float* __restrict__ g, const float* __restrict__ be,
                                               unsigned short* __restrict__ f1){
  const int t = threadIdx.x;
  const int n = blockIdx.y;
  const int co0 = blockIdx.x * 4;
  __shared__ float plane[3][68*72];
  __shared__ float redS[16], redQ[16];
  float* pl = (float*)plane;
  for (int k = t; k < 3*68*72; k += 256) pl[k] = 0.f;
  __syncthreads();
  for (int f4 = t; f4 < 3*1024; f4 += 256){
    int ci = f4 >> 10, rem = f4 & 1023;
    int ih = rem >> 4, iw4 = (rem & 15) << 2;
    float4 v = *(const float4*)&x[((n*3 + ci) << 12) + (ih << 6) + iw4];
    *(float4*)&plane[ci][(ih+2)*72 + iw4 + 4] = v;
  }
  __syncthreads();
  float acc[4][4] = {};
  int base[4];
  #pragma unroll
  for (int m = 0; m < 4; m++){
    int px = t + (m << 8);
    int oh = px >> 5, ow = px & 31;
    base[m] = (oh*2)*72 + ow*2 + 2;
  }
  #pragma unroll
  for (int ci = 0; ci < 3; ci++){
    const float* P = plane[ci];
    const float* W = wt + ci*25*64 + co0;
    #pragma unroll
    for (int kh = 0; kh < 5; kh++){
      #pragma unroll
      for (int kw = 0; kw < 5; kw++){
        const float* Wp = W + (kh*5+kw)*64;
        float w0 = Wp[0], w1 = Wp[1], w2 = Wp[2], w3 = Wp[3];
        #pragma unroll
        for (int m = 0; m < 4; m++){
          float v = P[base[m] + kh*72 + kw];
          acc[m][0] += v*w0; acc[m][1] += v*w1; acc[m][2] += v*w2; acc[m][3] += v*w3;
        }
      }
    }
  }
  int wid = t >> 6;
  #pragma unroll
  for (int c = 0; c < 4; c++){
    float s = acc[0][c]+acc[1][c]+acc[2][c]+acc[3][c];
    float q = acc[0][c]*acc[0][c]+acc[1][c]*acc[1][c]+acc[2][c]*acc[2][c]+acc[3][c]*acc[3][c];
    s = wred64(s); q = wred64(q);
    if ((t & 63) == 0){ redS[wid*4+c] = s; redQ[wid*4+c] = q; }
  }
  __syncthreads();
  float gmv[4], btv[4];
  #pragma unroll
  for (int c = 0; c < 4; c++){
    float S = redS[c] + redS[4+c] + redS[8+c] + redS[12+c];
    float Q = redQ[c] + redQ[4+c] + redQ[8+c] + redQ[12+c];
    float mu = S * (1.f/1024.f);
    float var = Q * (1.f/1024.f) - mu*mu;
    gmv[c] = g[co0+c] * rsqrtf(var + EPSF);
    btv[c] = be[co0+c] - mu*gmv[c];
  }
  #pragma unroll
  for (int m = 0; m < 4; m++){
    int px = t + (m << 8);
    ushort4 h;
    h.x = cvt_bf16(lrelu(acc[m][0]*gmv[0]+btv[0]));
    h.y = cvt_bf16(lrelu(acc[m][1]*gmv[1]+btv[1]));
    h.z = cvt_bf16(lrelu(acc[m][2]*gmv[2]+btv[2]));
    h.w = cvt_bf16(lrelu(acc[m][3]*gmv[3]+btv[3]));
    *(ushort4*)&f1[(((n<<10)+px)<<6) + co0] = h;
  }
}

// ---- conv2 MFMA: f1 NHWC bf16 (256,32,32,64) k5 s2 p2 -> f2raw NHWC bf16 (256,16,16,128)
// block = half image (128 px rows) x 128 co; 4 waves row-split; stats via atomics.
__global__ __launch_bounds__(256) void conv2_k(const unsigned short* __restrict__ fin,
                                               const unsigned short* __restrict__ wb,
                                               float* __restrict__ S2, float* __restrict__ Q2,
                                               unsigned short* __restrict__ fout){
  const int t = threadIdx.x;
  const int half = blockIdx.x, n = blockIdx.y;
  const int w = t>>6, lane = t&63, q = lane>>4, l16 = lane&15;
  __shared__ unsigned short tile[684*36];   // [19 tih][36 tiw] cells x 36-elt (pad) ~49.2 KB
  floatx4 acc[2][8];
  #pragma unroll
  for (int rg=0;rg<2;rg++)
    #pragma unroll
    for (int cg=0;cg<8;cg++) acc[rg][cg] = (floatx4){0.f,0.f,0.f,0.f};
  int abase[2];
  #pragma unroll
  for (int rg=0;rg<2;rg++){
    int r = w*32 + rg*16 + l16;
    int oh = r>>4, ow = r&15;
    abase[rg] = ((2*oh)*36 + 2*ow)*36 + q*8;
  }
  const unsigned short* bp[8];
  #pragma unroll
  for (int cg=0;cg<8;cg++) bp[cg] = wb + (cg*16+l16)*1600 + q*8;

  for (int cc = 0; cc < 64; cc += 32){
    if (cc) __syncthreads();
    #pragma unroll
    for (int it=0; it<11; it++){
      int idx = it*256 + t;
      if (idx < 2736){
        int cell = idx>>2, ci0 = (idx&3)<<3;
        int tih = cell/36, tiw = cell - tih*36;
        int ih = half*16 + tih - 2, iw = tiw - 2;
        uint4 v = {0u,0u,0u,0u};
        if ((unsigned)ih < 32u && (unsigned)iw < 32u)
          v = *(const uint4*)&fin[(((n*32+ih)*32 + iw)<<6) + cc + ci0];
        *(uint2*)&tile[cell*36+ci0]   = make_uint2(v.x, v.y);
        *(uint2*)&tile[cell*36+ci0+4] = make_uint2(v.z, v.w);
      }
    }
    __syncthreads();
    for (int tap=0; tap<25; tap++){
      int kh = tap/5, kw = tap - kh*5;
      int aoff = (kh*36+kw)*36;
      short8v a[2], b[8];
      #pragma unroll
      for (int rg=0;rg<2;rg++) a[rg] = ld_frag(&tile[abase[rg]+aoff]);
      #pragma unroll
      for (int cg=0;cg<8;cg++) b[cg] = *(const short8v*)&bp[cg][tap*64+cc];
      #pragma unroll
      for (int rg=0;rg<2;rg++)
        #pragma unroll
        for (int cg=0;cg<8;cg++)
          acc[rg][cg] = __builtin_amdgcn_mfma_f32_16x16x32_bf16(a[rg], b[cg], acc[rg][cg], 0,0,0);
    }
  }
  #pragma unroll
  for (int cg=0;cg<8;cg++){
    float s=0.f, qq=0.f;
    #pragma unroll
    for (int rg=0;rg<2;rg++)
      #pragma unroll
      for (int e=0;e<4;e++){ float xv = acc[rg][cg][e]; s += xv; qq += xv*xv; }
    s  += __shfl_xor(s,16,64);  s  += __shfl_xor(s,32,64);
    qq += __shfl_xor(qq,16,64); qq += __shfl_xor(qq,32,64);
    if (q == 0){
      atomicAdd(&S2[n*128 + cg*16 + l16], s);
      atomicAdd(&Q2[n*128 + cg*16 + l16], qq);
    }
  }
  #pragma unroll
  for (int rg=0;rg<2;rg++)
    #pragma unroll
    for (int cg=0;cg<8;cg++)
      #pragma unroll
      for (int e=0;e<4;e++){
        int r = w*32 + rg*16 + q*4 + e;
        int px = half*128 + r;
        fout[((n<<8) + px)*128 + cg*16 + l16] = cvt_bf16(acc[rg][cg][e]);
      }
}

// normalize+lrelu pass for conv2 (in-place on f2 bf16)
__global__ __launch_bounds__(256) void norm2_k(const float* __restrict__ S2, const float* __restrict__ Q2,
                                               const float* __restrict__ g, const float* __restrict__ be,
                                               unsigned short* __restrict__ f){
  const int n = blockIdx.x, t = threadIdx.x;
  __shared__ float gm[128], bt[128];
  if (t < 128){
    float S = S2[n*128+t], Q = Q2[n*128+t];
    float mu = S*(1.f/256.f), var = Q*(1.f/256.f) - mu*mu;
    float r = rsqrtf(var+EPSF)*g[t];
    gm[t] = r; bt[t] = be[t] - mu*r;
  }
  __syncthreads();
  #pragma unroll
  for (int it=0; it<32; it++){
    int idx = it*256 + t;          // ushort4 id, 8192 per image
    int e = idx<<2, c0 = e & 127;
    ushort4 v = *(ushort4*)&f[(n<<15) + e];
    v.x = cvt_bf16(lrelu(bf2f(v.x)*gm[c0+0]+bt[c0+0]));
    v.y = cvt_bf16(lrelu(bf2f(v.y)*gm[c0+1]+bt[c0+1]));
    v.z = cvt_bf16(lrelu(bf2f(v.z)*gm[c0+2]+bt[c0+2]));
    v.w = cvt_bf16(lrelu(bf2f(v.w)*gm[c0+3]+bt[c0+3]));
    *(ushort4*)&f[(n<<15) + e] = v;
  }
}

// ---- conv3 MFMA: f2 (256,16,16,128) k5 s2 p2 -> f3 (256,8,8,256), fused IN+lrelu.
// block = 1 image (64 rows) x 256 co; waves 2x2 (rw=row half, cw=col half).
__global__ __launch_bounds__(256) void conv3_k(const unsigned short* __restrict__ fin,
                                               const unsigned short* __restrict__ wb,
                                               const float* __restrict__ g, const float* __restrict__ be,
                                               unsigned short* __restrict__ fout){
  const int t = threadIdx.x, n = blockIdx.x;
  const int w = t>>6, lane = t&63, q = lane>>4, l16 = lane&15;
  const int rw = w&1, cw = w>>1;
  __shared__ unsigned short tile[361*36];   // [19][19] cells x 36 ~26 KB
  __shared__ float SQs[4][128], SQq[4][128];
  floatx4 acc[2][8];
  #pragma unroll
  for (int rg=0;rg<2;rg++)
    #pragma unroll
    for (int cg=0;cg<8;cg++) acc[rg][cg] = (floatx4){0.f,0.f,0.f,0.f};
  int abase[2];
  #pragma unroll
  for (int rg=0;rg<2;rg++){
    int r = rw*32 + rg*16 + l16;
    int oh = r>>3, ow = r&7;
    abase[rg] = ((2*oh)*19 + 2*ow)*36 + q*8;
  }
  const unsigned short* bp[8];
  #pragma unroll
  for (int cg=0;cg<8;cg++) bp[cg] = wb + (cw*128 + cg*16 + l16)*3200 + q*8;

  for (int cc = 0; cc < 128; cc += 32){
    if (cc) __syncthreads();
    #pragma unroll
    for (int it=0; it<6; it++){
      int idx = it*256 + t;
      if (idx < 1444){
        int cell = idx>>2, ci0 = (idx&3)<<3;
        int tih = cell/19, tiw = cell - tih*19;
        int ih = tih - 2, iw = tiw - 2;
        uint4 v = {0u,0u,0u,0u};
        if ((unsigned)ih < 16u && (unsigned)iw < 16u)
          v = *(const uint4*)&fin[(((n*16+ih)*16 + iw)<<7) + cc + ci0];
        *(uint2*)&tile[cell*36+ci0]   = make_uint2(v.x, v.y);
        *(uint2*)&tile[cell*36+ci0+4] = make_uint2(v.z, v.w);
      }
    }
    __syncthreads();
    for (int tap=0; tap<25; tap++){
      int kh = tap/5, kw = tap - kh*5;
      int aoff = (kh*19+kw)*36;
      short8v a[2], b[8];
      #pragma unroll
      for (int rg=0;rg<2;rg++) a[rg] = ld_frag(&tile[abase[rg]+aoff]);
      #pragma unroll
      for (int cg=0;cg<8;cg++) b[cg] = *(const short8v*)&bp[cg][tap*128+cc];
      #pragma unroll
      for (int rg=0;rg<2;rg++)
        #pragma unroll
        for (int cg=0;cg<8;cg++)
          acc[rg][cg] = __builtin_amdgcn_mfma_f32_16x16x32_bf16(a[rg], b[cg], acc[rg][cg], 0,0,0);
    }
  }
  #pragma unroll
  for (int cg=0;cg<8;cg++){
    float s=0.f, qq=0.f;
    #pragma unroll
    for (int rg=0;rg<2;rg++)
      #pragma unroll
      for (int e=0;e<4;e++){ float xv = acc[rg][cg][e]; s += xv; qq += xv*xv; }
    s  += __shfl_xor(s,16,64);  s  += __shfl_xor(s,32,64);
    qq += __shfl_xor(qq,16,64); qq += __shfl_xor(qq,32,64);
    if (q == 0){ SQs[w][cg*16+l16] = s; SQq[w][cg*16+l16] = qq; }
  }
  __syncthreads();
  #pragma unroll
  for (int cg=0;cg<8;cg++){
    int lcol = cg*16 + l16, colg = cw*128 + lcol;
    float S = SQs[2*cw][lcol] + SQs[2*cw+1][lcol];
    float Q = SQq[2*cw][lcol] + SQq[2*cw+1][lcol];
    float mu = S*(1.f/64.f), var = Q*(1.f/64.f) - mu*mu;
    float gmv = rsqrtf(var+EPSF)*g[colg];
    float btv = be[colg] - mu*gmv;
    #pragma unroll
    for (int rg=0;rg<2;rg++)
      #pragma unroll
      for (int e=0;e<4;e++){
        int r = rw*32 + rg*16 + q*4 + e;
        fout[((n<<6) + r)*256 + colg] = cvt_bf16(lrelu(acc[rg][cg][e]*gmv+btv));
      }
  }
}

// ---- conv4 MFMA: f3 (256,8,8,256) k3 s2 p1 -> feat fp32 NCHW-flat (256,4096), fused IN+lrelu.
// block = 4 images (64 rows) x 256 co; waves 2x2; per-(rg)=image stats in-wave.
__global__ __launch_bounds__(256) void conv4_k(const unsigned short* __restrict__ fin,
                                               const unsigned short* __restrict__ wb,
                                               const float* __restrict__ g, const float* __restrict__ be,
                                               float* __restrict__ feat){
  const int t = threadIdx.x, n0 = blockIdx.x*4;
  const int w = t>>6, lane = t&63, q = lane>>4, l16 = lane&15;
  const int rw = w&1, cw = w>>1;
  __shared__ unsigned short tile[324*36];   // 4 imgs x [9][9] cells x 36 ~23 KB
  floatx4 acc[2][8];
  #pragma unroll
  for (int rg=0;rg<2;rg++)
    #pragma unroll
    for (int cg=0;cg<8;cg++) acc[rg][cg] = (floatx4){0.f,0.f,0.f,0.f};
  int abase[2];
  #pragma unroll
  for (int rg=0;rg<2;rg++){
    int r = rw*32 + rg*16 + l16;
    int img = r>>4, px = r&15, oh = px>>2, ow = px&3;
    abase[rg] = (img*81 + (2*oh)*9 + 2*ow)*36 + q*8;
  }
  const unsigned short* bp[8];
  #pragma unroll
  for (int cg=0;cg<8;cg++) bp[cg] = wb + (cw*128 + cg*16 + l16)*2304 + q*8;

  for (int cc = 0; cc < 256; cc += 32){
    if (cc) __syncthreads();
    #pragma unroll
    for (int it=0; it<6; it++){
      int idx = it*256 + t;
      if (idx < 1296){
        int cell = idx>>2, ci0 = (idx&3)<<3;
        int img = cell/81, c2 = cell - img*81;
        int tih = c2/9, tiw = c2 - tih*9;
        int ih = tih - 1, iw = tiw - 1;
        uint4 v = {0u,0u,0u,0u};
        if ((unsigned)ih < 8u && (unsigned)iw < 8u)
          v = *(const uint4*)&fin[((((n0+img)*8+ih)*8 + iw)<<8) + cc + ci0];
        *(uint2*)&tile[cell*36+ci0]   = make_uint2(v.x, v.y);
        *(uint2*)&tile[cell*36+ci0+4] = make_uint2(v.z, v.w);
      }
    }
    __syncthreads();
    for (int tap=0; tap<9; tap++){
      int kh = tap/3, kw = tap - kh*3;
      int aoff = (kh*9+kw)*36;
      short8v a[2], b[8];
      #pragma unroll
      for (int rg=0;rg<2;rg++) a[rg] = ld_frag(&tile[abase[rg]+aoff]);
      #pragma unroll
      for (int cg=0;cg<8;cg++) b[cg] = *(const short8v*)&bp[cg][tap*256+cc];
      #pragma unroll
      for (int rg=0;rg<2;rg++)
        #pragma unroll
        for (int cg=0;cg<8;cg++)
          acc[rg][cg] = __builtin_amdgcn_mfma_f32_16x16x32_bf16(a[rg], b[cg], acc[rg][cg], 0,0,0);
    }
  }
  #pragma unroll
  for (int rg=0;rg<2;rg++){
    int nimg = n0 + rw*2 + rg;
    #pragma unroll
    for (int cg=0;cg<8;cg++){
      int colg = cw*128 + cg*16 + l16;
      float s=0.f, qq=0.f;
      #pragma unroll
      for (int e=0;e<4;e++){ float xv = acc[rg][cg][e]; s += xv; qq += xv*xv; }
      s  += __shfl_xor(s,16,64);  s  += __shfl_xor(s,32,64);
      qq += __shfl_xor(qq,16,64); qq += __shfl_xor(qq,32,64);
      float mu = s*(1.f/16.f), var = qq*(1.f/16.f) - mu*mu;
      float gmv = rsqrtf(var+EPSF)*g[colg];
      float btv = be[colg] - mu*gmv;
      #pragma unroll
      for (int e=0;e<4;e++){
        int px = q*4 + e;
        feat[(nimg<<12) + (colg<<4) + px] = lrelu(acc[rg][cg][e]*gmv+btv);
      }
    }
  }
}

// ---- M einsum: Cp[z] = feat(256x4096) @ T(4096x3200), K split 8x512. 128x128 tile, 8x8 micro.
__global__ __launch_bounds__(256) void gemmM_k(const float* __restrict__ A, const float* __restrict__ B,
                                               float* __restrict__ Cp){
  const int t = threadIdx.x;
  const int on0 = blockIdx.x << 7;
  const int b0 = blockIdx.y << 7;
  const int k0 = blockIdx.z << 9;
  __shared__ float Asm[32][132];
  __shared__ float Bsm[32][132];
  const int tx = t & 15, ty = t >> 4;
  float acc[8][8] = {};
  for (int kk = 0; kk < 512; kk += 32){
    #pragma unroll
    for (int m = 0; m < 4; m++){
      int f4 = t + (m << 8);
      int b = f4 >> 3, seg = f4 & 7;
      float4 v = *(const float4*)&A[((b0 + b) << 12) + k0 + kk + (seg << 2)];
      Asm[(seg<<2)+0][b] = v.x; Asm[(seg<<2)+1][b] = v.y; Asm[(seg<<2)+2][b] = v.z; Asm[(seg<<2)+3][b] = v.w;
    }
    #pragma unroll
    for (int m = 0; m < 4; m++){
      int f4 = t + (m << 8);
      int ii = f4 >> 5, seg = f4 & 31;
      float4 v = *(const float4*)&B[(k0 + kk + ii)*3200 + on0 + (seg << 2)];
      *(float4*)&Bsm[ii][seg << 2] = v;
    }
    __syncthreads();
    #pragma unroll
    for (int ii = 0; ii < 32; ii++){
      float4 a0 = *(const float4*)&Asm[ii][ty << 3];
      float4 a1 = *(const float4*)&Asm[ii][(ty << 3) + 4];
      float4 c0v = *(const float4*)&Bsm[ii][tx << 3];
      float4 c1v = *(const float4*)&Bsm[ii][(tx << 3) + 4];
      float av[8] = {a0.x,a0.y,a0.z,a0.w,a1.x,a1.y,a1.z,a1.w};
      float bw[8] = {c0v.x,c0v.y,c0v.z,c0v.w,c1v.x,c1v.y,c1v.z,c1v.w};
      #pragma unroll
      for (int p = 0; p < 8; p++)
        #pragma unroll
        for (int qq = 0; qq < 8; qq++) acc[p][qq] += av[p]*bw[qq];
    }
    __syncthreads();
  }
  float* C = Cp + blockIdx.z * 819200;
  #pragma unroll
  for (int p = 0; p < 8; p++){
    int row = b0 + (ty << 3) + p;
    float4 v0 = {acc[p][0],acc[p][1],acc[p][2],acc[p][3]};
    float4 v1 = {acc[p][4],acc[p][5],acc[p][6],acc[p][7]};
    *(float4*)&C[row*3200 + on0 + (tx << 3)] = v0;
    *(float4*)&C[row*3200 + on0 + (tx << 3) + 4] = v1;
  }
}

__global__ __launch_bounds__(256) void reduceM_k(const float* __restrict__ Cp, float* __restrict__ M){
  int i4 = blockIdx.x * 256 + threadIdx.x;
  if (i4 >= 204800) return;
  float4 r = {0,0,0,0};
  #pragma unroll
  for (int s = 0; s < 8; s++){
    float4 v = *(const float4*)&Cp[s*819200 + (i4 << 2)];
    r.x += v.x; r.y += v.y; r.z += v.z; r.w += v.w;
  }
  *(float4*)&M[i4 << 2] = r;
}

// ---- pairwise: o_b[j,o] = sum_i exp(-sum_k |M[i,o,k]-M[j,o,k]|) - 1
__global__ __launch_bounds__(256) void pair_k(const float* __restrict__ M, float* __restrict__ ob){
  const int j = blockIdx.x, t = threadIdx.x;
  __shared__ float Mj[3200];
  __shared__ float red[256];
  for (int k = t; k < 3200; k += 256) Mj[k] = M[j*3200 + k];
  __syncthreads();
  const int o = t & 63, ss = t >> 6;
  const float2* mj = (const float2*)&Mj[o*50];
  float sum = 0.f;
  for (int i = ss << 6; i < (ss << 6) + 64; i++){
    const float2* mi = (const float2*)&M[i*3200 + o*50];
    float d = 0.f;
    #pragma unroll
    for (int k2 = 0; k2 < 25; k2++){
      float2 a = mi[k2], b = mj[k2];
      d += fabsf(a.x - b.x) + fabsf(a.y - b.y);
    }
    sum += expf(-d);
  }
  red[(o << 2) + ss] = sum;
  __syncthreads();
  if (t < 64) ob[(j << 6) + t] = red[t<<2] + red[(t<<2)+1] + red[(t<<2)+2] + red[(t<<2)+3] - 1.0f;
}

// ---- fc: ypart[z] = mb(256x4160) @ fc_w(1000x4160)^T tile, K split 13x320.
__global__ __launch_bounds__(256) void gemmFC_k(const float* __restrict__ feat, const float* __restrict__ ob,
                                                const float* __restrict__ W, float* __restrict__ Cp){
  const int t = threadIdx.x;
  const int o0 = blockIdx.x << 7;
  const int b0 = blockIdx.y << 7;
  const int k0 = blockIdx.z * 320;
  __shared__ float Asm[32][132];
  __shared__ float Bsm[32][132];
  const int tx = t & 15, ty = t >> 4;
  float acc[8][8] = {};
  for (int kk = 0; kk < 320; kk += 32){
    #pragma unroll
    for (int m = 0; m < 4; m++){
      int f4 = t + (m << 8);
      int b = f4 >> 3, seg = f4 & 7;
      int i = k0 + kk + (seg << 2);
      float4 v;
      if (i < 4096) v = *(const float4*)&feat[((b0 + b) << 12) + i];
      else          v = *(const float4*)&ob[((b0 + b) << 6) + (i - 4096)];
      Asm[(seg<<2)+0][b] = v.x; Asm[(seg<<2)+1][b] = v.y; Asm[(seg<<2)+2][b] = v.z; Asm[(seg<<2)+3][b] = v.w;
    }
    #pragma unroll
    for (int m = 0; m < 4; m++){
      int f4 = t + (m << 8);
      int oo = f4 >> 3, seg = f4 & 7;
      float4 v = {0,0,0,0};
      if (o0 + oo < 1000) v = *(const float4*)&W[(o0 + oo)*4160 + k0 + kk + (seg << 2)];
      Bsm[(seg<<2)+0][oo] = v.x; Bsm[(seg<<2)+1][oo] = v.y; Bsm[(seg<<2)+2][oo] = v.z; Bsm[(seg<<2)+3][oo] = v.w;
    }
    __syncthreads();
    #pragma unroll
    for (int ii = 0; ii < 32; ii++){
      float4 a0 = *(const float4*)&Asm[ii][ty << 3];
      float4 a1 = *(const float4*)&Asm[ii][(ty << 3) + 4];
      float4 c0v = *(const float4*)&Bsm[ii][tx << 3];
      float4 c1v = *(const float4*)&Bsm[ii][(tx << 3) + 4];
      float av[8] = {a0.x,a0.y,a0.z,a0.w,a1.x,a1.y,a1.z,a1.w};
      float bw[8] = {c0v.x,c0v.y,c0v.z,c0v.w,c1v.x,c1v.y,c1v.z,c1v.w};
      #pragma unroll
      for (int p = 0; p < 8; p++)
        #pragma unroll
        for (int qq = 0; qq < 8; qq++) acc[p][qq] += av[p]*bw[qq];
    }
    __syncthreads();
  }
  float* C = Cp + blockIdx.z * 256000;
  #pragma unroll
  for (int p = 0; p < 8; p++){
    int row = b0 + (ty << 3) + p;
    #pragma unroll
    for (int qq = 0; qq < 8; qq++){
      int o = o0 + (tx << 3) + qq;
      if (o < 1000) C[row*1000 + o] = acc[p][qq];
    }
  }
}

__global__ __launch_bounds__(256) void reduceY_k(const float* __restrict__ Cp, const float* __restrict__ bias,
                                                 float* __restrict__ y){
  int idx = blockIdx.x * 256 + threadIdx.x;
  if (idx >= 256000) return;
  int o = idx % 1000;
  float r = bias[o];
  #pragma unroll
  for (int s = 0; s < 13; s++) r += Cp[s*256000 + idx];
  y[idx] = r;
}

extern "C" void kernel_launch(void* const* d_in, const int* in_sizes, int n_in,
                              void* d_out, int out_size, void* d_ws, size_t ws_size,
                              hipStream_t stream){
  const float* x   = (const float*)d_in[0];
  const float* w1  = (const float*)d_in[1];
  const float* g1  = (const float*)d_in[3];
  const float* be1 = (const float*)d_in[4];
  const float* w2  = (const float*)d_in[5];
  const float* g2  = (const float*)d_in[7];
  const float* be2 = (const float*)d_in[8];
  const float* w3  = (const float*)d_in[9];
  const float* g3  = (const float*)d_in[11];
  const float* be3 = (const float*)d_in[12];
  const float* w4  = (const float*)d_in[13];
  const float* g4  = (const float*)d_in[15];
  const float* be4 = (const float*)d_in[16];
  const float* T   = (const float*)d_in[17];
  const float* fcw = (const float*)d_in[18];
  const float* fcb = (const float*)d_in[19];
  float* out = (float*)d_out;
  float* ws  = (float*)d_ws;

  // workspace layout (float units)
  unsigned short* f1 = (unsigned short*)ws;                  // 16,777,216 bf16 (8,388,608 fl)
  unsigned short* f2 = (unsigned short*)(ws + 8388608);      //  8,388,608 bf16 (4,194,304 fl)
  unsigned short* f3 = (unsigned short*)(ws + 12582912);     //  4,194,304 bf16 (2,097,152 fl)
  float* wt1 = ws + 14680064;                                //      4,800
  unsigned short* wb2 = (unsigned short*)(ws + 14684864);    //    204,800 bf16 (102,400 fl)
  unsigned short* wb3 = (unsigned short*)(ws + 14787264);    //    819,200 bf16 (409,600 fl)
  unsigned short* wb4 = (unsigned short*)(ws + 15196864);    //    589,824 bf16 (294,912 fl)
  float* S2   = ws + 15491776;                               //     32,768
  float* Q2   = ws + 15524544;                               //     32,768  (end 15,557,312 fl = 62.2 MB)
  // aliases over dead f1/f2 region (gemm phase)
  float* Mp   = ws;                                          //  6,553,600
  float* Mb   = ws + 6553600;                                //    819,200
  float* obuf = ws + 7372800;                                //     16,384
  float* yp   = ws + 7389184;                                //  3,328,000 (ends 10,717,184 < 12,582,912)
  float* feat = out;                                         // (256,4096)
  float* y    = out + 1048576;                               // (256,1000)

  zero_k  <<<dim3(256),  256, 0, stream>>>(S2, 65536);       // zeros S2+Q2 (contiguous)
  wtrans_k<<<dim3(19),   256, 0, stream>>>(w1, wt1, 64, 75);
  wprep_k <<<dim3(800),  256, 0, stream>>>(w2, wb2, 128, 64, 25);
  wprep_k <<<dim3(3200), 256, 0, stream>>>(w3, wb3, 256, 128, 25);
  wprep_k <<<dim3(2304), 256, 0, stream>>>(w4, wb4, 256, 256, 9);

  conv1_k<<<dim3(16, 256), 256, 0, stream>>>(x,  wt1, g1, be1, f1);
  conv2_k<<<dim3(2, 256),  256, 0, stream>>>(f1, wb2, S2, Q2, f2);
  norm2_k<<<dim3(256),     256, 0, stream>>>(S2, Q2, g2, be2, f2);
  conv3_k<<<dim3(256),     256, 0, stream>>>(f2, wb3, g3, be3, f3);
  conv4_k<<<dim3(64),      256, 0, stream>>>(f3, wb4, g4, be4, feat);

  gemmM_k<<<dim3(25, 2, 8), 256, 0, stream>>>(feat, T, Mp);
  reduceM_k<<<dim3(800), 256, 0, stream>>>(Mp, Mb);
  pair_k<<<dim3(256), 256, 0, stream>>>(Mb, obuf);
  gemmFC_k<<<dim3(8, 2, 13), 256, 0, stream>>>(feat, obuf, fcw, yp);
  reduceY_k<<<dim3(1000), 256, 0, stream>>>(yp, fcb, y);
}

// Round 3
// 596.193 us; speedup vs baseline: 2.5493x; 1.4387x over previous
//
#include <hip/hip_runtime.h>
#include <hip/hip_fp16.h>
#include <math.h>

#define EPSF 1e-5f

typedef __attribute__((ext_vector_type(4))) float  floatx4;
typedef __attribute__((ext_vector_type(4))) short  short4v;
typedef __attribute__((ext_vector_type(8))) short  short8v;

__device__ __forceinline__ unsigned short cvt_bf16(float f){
  unsigned u = __float_as_uint(f);
  unsigned r = (u + 0x7FFFu + ((u >> 16) & 1u)) >> 16;
  return (unsigned short)r;
}
__device__ __forceinline__ float bf2f(unsigned short h){
  return __uint_as_float(((unsigned)h) << 16);
}
__device__ __forceinline__ short8v ld_frag(const unsigned short* p){
  short4v lo = *(const short4v*)p;
  short4v hi = *(const short4v*)(p + 4);
  return __builtin_shufflevector(lo, hi, 0,1,2,3,4,5,6,7);
}
__device__ __forceinline__ float lrelu(float x){ return x >= 0.f ? x : 0.2f*x; }

__global__ __launch_bounds__(256) void zero_k(float* __restrict__ p, int n){
  int i = blockIdx.x*256 + threadIdx.x;
  if (i < n) p[i] = 0.f;
}

// conv1 weights: w1[co][ci][5][5] -> wb1[co][128], k = (kh*6+kw)*4 + ci (pads zero)
__global__ __launch_bounds__(256) void wprep1_k(const float* __restrict__ w, unsigned short* __restrict__ wb){
  int idx = blockIdx.x*256 + threadIdx.x;
  if (idx >= 64*128) return;
  int co = idx >> 7, k = idx & 127;
  int tap6 = k >> 2, ci = k & 3;
  int kh = tap6 / 6, kw = tap6 - kh*6;
  float v = 0.f;
  if (ci < 3 && kw < 5 && kh < 5) v = w[(co*3 + ci)*25 + kh*5 + kw];
  wb[idx] = cvt_bf16(v);
}

// MFMA conv weights: w[co][ci][tap] fp32 -> wb[co][tap][ci] bf16
__global__ __launch_bounds__(256) void wprep_k(const float* __restrict__ w, unsigned short* __restrict__ wb,
                                               int CO, int CIN, int TAPS){
  int idx = blockIdx.x*256 + threadIdx.x;
  int tc = CIN*TAPS;
  if (idx >= CO*tc) return;
  int co = idx / tc, r = idx - co*tc;
  int tap = r / CIN, ci = r - tap*CIN;
  wb[idx] = cvt_bf16(w[(co*CIN + ci)*TAPS + tap]);
}

// ---- conv1 MFMA: x(256,3,64,64) fp32 -> f1raw NHWC bf16 (pre-norm) + gmbt1 per (n,co).
// block = 1 image; M=1024 px (64 mtiles of 16 ow), N=64 co, K=128 (30 padded taps x 4ch).
__global__ __launch_bounds__(256) void conv1_k(const float* __restrict__ x, const unsigned short* __restrict__ wb1,
                                               const float* __restrict__ g, const float* __restrict__ be,
                                               unsigned short* __restrict__ f1raw, float* __restrict__ gmbt1){
  const int t = threadIdx.x, n = blockIdx.x;
  const int w = t>>6, lane = t&63, q = lane>>4, l16 = lane&15;
  __shared__ unsigned short img[68*68*4];   // padded NHWC-4 bf16, 36992 B
  __shared__ float SQ[2][4][64];
  short8v bf[4][4];
  #pragma unroll
  for (int nt=0; nt<4; nt++)
    #pragma unroll
    for (int ks=0; ks<4; ks++)
      bf[nt][ks] = *(const short8v*)&wb1[(nt*16+l16)*128 + ks*32 + q*8];
  for (int i=t; i<9248; i+=256) ((unsigned*)img)[i] = 0u;
  __syncthreads();
  for (int idx=t; idx<3072; idx+=256){
    int ci = idx>>10, rem = idx&1023, ih = rem>>4, iw4 = (rem&15)<<2;
    float4 v = *(const float4*)&x[((n*3+ci)<<12) + (ih<<6) + iw4];
    int base = ((ih+2)*68 + (iw4+2))*4 + ci;
    img[base]    = cvt_bf16(v.x);
    img[base+4]  = cvt_bf16(v.y);
    img[base+8]  = cvt_bf16(v.z);
    img[base+12] = cvt_bf16(v.w);
  }
  __syncthreads();
  float sreg[4] = {0,0,0,0}, qreg[4] = {0,0,0,0};
  #pragma unroll
  for (int grp=0; grp<2; grp++){
    floatx4 acc[8][4];
    #pragma unroll
    for (int mi=0;mi<8;mi++)
      #pragma unroll
      for (int nt=0;nt<4;nt++) acc[mi][nt] = (floatx4){0.f,0.f,0.f,0.f};
    #pragma unroll
    for (int mi=0; mi<8; mi++){
      int mt = w*16 + grp*8 + mi;
      int oh = mt>>1, ow = ((mt&1)<<4) + l16;
      #pragma unroll
      for (int ks=0; ks<4; ks++){
        int t0 = ks*8 + 2*q;
        int kh = t0/6, kw = t0 - kh*6;
        short8v a = *(const short8v*)&img[((oh*2+kh)*68 + (ow*2+kw))*4];
        #pragma unroll
        for (int nt=0; nt<4; nt++)
          acc[mi][nt] = __builtin_amdgcn_mfma_f32_16x16x32_bf16(a, bf[nt][ks], acc[mi][nt], 0,0,0);
      }
    }
    #pragma unroll
    for (int mi=0;mi<8;mi++){
      int mt = w*16 + grp*8 + mi;
      #pragma unroll
      for (int nt=0;nt<4;nt++)
        #pragma unroll
        for (int e=0;e<4;e++){
          float v = acc[mi][nt][e];
          sreg[nt] += v; qreg[nt] += v*v;
          int px = (mt<<4) + (q<<2) + e;
          f1raw[(((n<<10)+px)<<6) + (nt<<4) + l16] = cvt_bf16(v);
        }
    }
  }
  #pragma unroll
  for (int nt=0;nt<4;nt++){
    float s = sreg[nt], qq = qreg[nt];
    s  += __shfl_xor(s,16,64);  s  += __shfl_xor(s,32,64);
    qq += __shfl_xor(qq,16,64); qq += __shfl_xor(qq,32,64);
    if (q==0){ SQ[0][w][(nt<<4)+l16] = s; SQ[1][w][(nt<<4)+l16] = qq; }
  }
  __syncthreads();
  if (t < 64){
    float S = SQ[0][0][t]+SQ[0][1][t]+SQ[0][2][t]+SQ[0][3][t];
    float Q = SQ[1][0][t]+SQ[1][1][t]+SQ[1][2][t]+SQ[1][3][t];
    float mu = S*(1.f/1024.f), var = Q*(1.f/1024.f)-mu*mu;
    float gm = g[t]*rsqrtf(var+EPSF);
    gmbt1[((n<<6)+t)*2]   = gm;
    gmbt1[((n<<6)+t)*2+1] = be[t] - mu*gm;
  }
}

// ---- conv2 MFMA: f1raw (IN+lrelu applied during staging via gmbt1) -> f2 raw + S2/Q2 atomics.
__global__ __launch_bounds__(256) void conv2_k(const unsigned short* __restrict__ fin,
                                               const unsigned short* __restrict__ wb,
                                               const float* __restrict__ gmbt1,
                                               float* __restrict__ S2, float* __restrict__ Q2,
                                               unsigned short* __restrict__ fout){
  const int t = threadIdx.x;
  const int half = blockIdx.x, n = blockIdx.y;
  const int w = t>>6, lane = t&63, q = lane>>4, l16 = lane&15;
  __shared__ unsigned short tile[684*36];
  __shared__ float gmA[64], btA[64];
  if (t < 64){
    gmA[t] = gmbt1[((n<<6)+t)*2];
    btA[t] = gmbt1[((n<<6)+t)*2+1];
  }
  __syncthreads();
  floatx4 acc[2][8];
  #pragma unroll
  for (int rg=0;rg<2;rg++)
    #pragma unroll
    for (int cg=0;cg<8;cg++) acc[rg][cg] = (floatx4){0.f,0.f,0.f,0.f};
  int abase[2];
  #pragma unroll
  for (int rg=0;rg<2;rg++){
    int r = w*32 + rg*16 + l16;
    int oh = r>>4, ow = r&15;
    abase[rg] = ((2*oh)*36 + 2*ow)*36 + q*8;
  }
  const unsigned short* bp[8];
  #pragma unroll
  for (int cg=0;cg<8;cg++) bp[cg] = wb + (cg*16+l16)*1600 + q*8;

  for (int cc = 0; cc < 64; cc += 32){
    if (cc) __syncthreads();
    #pragma unroll
    for (int it=0; it<11; it++){
      int idx = it*256 + t;
      if (idx < 2736){
        int cell = idx>>2, ci0 = (idx&3)<<3;
        int tih = cell/36, tiw = cell - tih*36;
        int ih = half*16 + tih - 2, iw = tiw - 2;
        uint4 v = {0u,0u,0u,0u};
        if ((unsigned)ih < 32u && (unsigned)iw < 32u){
          v = *(const uint4*)&fin[(((n*32+ih)*32 + iw)<<6) + cc + ci0];
          unsigned short* hp = (unsigned short*)&v;
          #pragma unroll
          for (int jj=0;jj<8;jj++){
            int c = cc + ci0 + jj;
            hp[jj] = cvt_bf16(lrelu(bf2f(hp[jj])*gmA[c]+btA[c]));
          }
        }
        *(uint2*)&tile[cell*36+ci0]   = make_uint2(v.x, v.y);
        *(uint2*)&tile[cell*36+ci0+4] = make_uint2(v.z, v.w);
      }
    }
    __syncthreads();
    for (int tap=0; tap<25; tap++){
      int kh = tap/5, kw = tap - kh*5;
      int aoff = (kh*36+kw)*36;
      short8v a[2], b[8];
      #pragma unroll
      for (int rg=0;rg<2;rg++) a[rg] = ld_frag(&tile[abase[rg]+aoff]);
      #pragma unroll
      for (int cg=0;cg<8;cg++) b[cg] = *(const short8v*)&bp[cg][tap*64+cc];
      #pragma unroll
      for (int rg=0;rg<2;rg++)
        #pragma unroll
        for (int cg=0;cg<8;cg++)
          acc[rg][cg] = __builtin_amdgcn_mfma_f32_16x16x32_bf16(a[rg], b[cg], acc[rg][cg], 0,0,0);
    }
  }
  #pragma unroll
  for (int cg=0;cg<8;cg++){
    float s=0.f, qq=0.f;
    #pragma unroll
    for (int rg=0;rg<2;rg++)
      #pragma unroll
      for (int e=0;e<4;e++){ float xv = acc[rg][cg][e]; s += xv; qq += xv*xv; }
    s  += __shfl_xor(s,16,64);  s  += __shfl_xor(s,32,64);
    qq += __shfl_xor(qq,16,64); qq += __shfl_xor(qq,32,64);
    if (q == 0){
      atomicAdd(&S2[n*128 + cg*16 + l16], s);
      atomicAdd(&Q2[n*128 + cg*16 + l16], qq);
    }
  }
  #pragma unroll
  for (int rg=0;rg<2;rg++)
    #pragma unroll
    for (int cg=0;cg<8;cg++)
      #pragma unroll
      for (int e=0;e<4;e++){
        int r = w*32 + rg*16 + q*4 + e;
        int px = half*128 + r;
        fout[((n<<8) + px)*128 + cg*16 + l16] = cvt_bf16(acc[rg][cg][e]);
      }
}

// ---- conv3 MFMA: f2 raw (IN2+lrelu applied during staging from S2/Q2) -> f3 normalized bf16.
__global__ __launch_bounds__(256) void conv3_k(const unsigned short* __restrict__ fin,
                                               const unsigned short* __restrict__ wb,
                                               const float* __restrict__ S2, const float* __restrict__ Q2,
                                               const float* __restrict__ g2, const float* __restrict__ be2,
                                               const float* __restrict__ g, const float* __restrict__ be,
                                               unsigned short* __restrict__ fout){
  const int t = threadIdx.x, n = blockIdx.x;
  const int w = t>>6, lane = t&63, q = lane>>4, l16 = lane&15;
  const int rw = w&1, cw = w>>1;
  __shared__ unsigned short tile[361*36];
  __shared__ float SQs[4][128], SQq[4][128];
  __shared__ float gmA[128], btA[128];
  if (t < 128){
    float S = S2[n*128+t], Q = Q2[n*128+t];
    float mu = S*(1.f/256.f), var = Q*(1.f/256.f) - mu*mu;
    float r = rsqrtf(var+EPSF)*g2[t];
    gmA[t] = r; btA[t] = be2[t] - mu*r;
  }
  __syncthreads();
  floatx4 acc[2][8];
  #pragma unroll
  for (int rg=0;rg<2;rg++)
    #pragma unroll
    for (int cg=0;cg<8;cg++) acc[rg][cg] = (floatx4){0.f,0.f,0.f,0.f};
  int abase[2];
  #pragma unroll
  for (int rg=0;rg<2;rg++){
    int r = rw*32 + rg*16 + l16;
    int oh = r>>3, ow = r&7;
    abase[rg] = ((2*oh)*19 + 2*ow)*36 + q*8;
  }
  const unsigned short* bp[8];
  #pragma unroll
  for (int cg=0;cg<8;cg++) bp[cg] = wb + (cw*128 + cg*16 + l16)*3200 + q*8;

  for (int cc = 0; cc < 128; cc += 32){
    if (cc) __syncthreads();
    #pragma unroll
    for (int it=0; it<6; it++){
      int idx = it*256 + t;
      if (idx < 1444){
        int cell = idx>>2, ci0 = (idx&3)<<3;
        int tih = cell/19, tiw = cell - tih*19;
        int ih = tih - 2, iw = tiw - 2;
        uint4 v = {0u,0u,0u,0u};
        if ((unsigned)ih < 16u && (unsigned)iw < 16u){
          v = *(const uint4*)&fin[(((n*16+ih)*16 + iw)<<7) + cc + ci0];
          unsigned short* hp = (unsigned short*)&v;
          #pragma unroll
          for (int jj=0;jj<8;jj++){
            int c = cc + ci0 + jj;
            hp[jj] = cvt_bf16(lrelu(bf2f(hp[jj])*gmA[c]+btA[c]));
          }
        }
        *(uint2*)&tile[cell*36+ci0]   = make_uint2(v.x, v.y);
        *(uint2*)&tile[cell*36+ci0+4] = make_uint2(v.z, v.w);
      }
    }
    __syncthreads();
    for (int tap=0; tap<25; tap++){
      int kh = tap/5, kw = tap - kh*5;
      int aoff = (kh*19+kw)*36;
      short8v a[2], b[8];
      #pragma unroll
      for (int rg=0;rg<2;rg++) a[rg] = ld_frag(&tile[abase[rg]+aoff]);
      #pragma unroll
      for (int cg=0;cg<8;cg++) b[cg] = *(const short8v*)&bp[cg][tap*128+cc];
      #pragma unroll
      for (int rg=0;rg<2;rg++)
        #pragma unroll
        for (int cg=0;cg<8;cg++)
          acc[rg][cg] = __builtin_amdgcn_mfma_f32_16x16x32_bf16(a[rg], b[cg], acc[rg][cg], 0,0,0);
    }
  }
  #pragma unroll
  for (int cg=0;cg<8;cg++){
    float s=0.f, qq=0.f;
    #pragma unroll
    for (int rg=0;rg<2;rg++)
      #pragma unroll
      for (int e=0;e<4;e++){ float xv = acc[rg][cg][e]; s += xv; qq += xv*xv; }
    s  += __shfl_xor(s,16,64);  s  += __shfl_xor(s,32,64);
    qq += __shfl_xor(qq,16,64); qq += __shfl_xor(qq,32,64);
    if (q == 0){ SQs[w][cg*16+l16] = s; SQq[w][cg*16+l16] = qq; }
  }
  __syncthreads();
  #pragma unroll
  for (int cg=0;cg<8;cg++){
    int lcol = cg*16 + l16, colg = cw*128 + lcol;
    float S = SQs[2*cw][lcol] + SQs[2*cw+1][lcol];
    float Q = SQq[2*cw][lcol] + SQq[2*cw+1][lcol];
    float mu = S*(1.f/64.f), var = Q*(1.f/64.f) - mu*mu;
    float gmv = rsqrtf(var+EPSF)*g[colg];
    float btv = be[colg] - mu*gmv;
    #pragma unroll
    for (int rg=0;rg<2;rg++)
      #pragma unroll
      for (int e=0;e<4;e++){
        int r = rw*32 + rg*16 + q*4 + e;
        fout[((n<<6) + r)*256 + colg] = cvt_bf16(lrelu(acc[rg][cg][e]*gmv+btv));
      }
  }
}

// ---- conv4 MFMA: f3 -> feat fp32 (d_out) + featb bf16, fused IN+lrelu.
__global__ __launch_bounds__(256) void conv4_k(const unsigned short* __restrict__ fin,
                                               const unsigned short* __restrict__ wb,
                                               const float* __restrict__ g, const float* __restrict__ be,
                                               float* __restrict__ feat, unsigned short* __restrict__ featb){
  const int t = threadIdx.x, n0 = blockIdx.x*4;
  const int w = t>>6, lane = t&63, q = lane>>4, l16 = lane&15;
  const int rw = w&1, cw = w>>1;
  __shared__ unsigned short tile[324*36];
  floatx4 acc[2][8];
  #pragma unroll
  for (int rg=0;rg<2;rg++)
    #pragma unroll
    for (int cg=0;cg<8;cg++) acc[rg][cg] = (floatx4){0.f,0.f,0.f,0.f};
  int abase[2];
  #pragma unroll
  for (int rg=0;rg<2;rg++){
    int r = rw*32 + rg*16 + l16;
    int img = r>>4, px = r&15, oh = px>>2, ow = px&3;
    abase[rg] = (img*81 + (2*oh)*9 + 2*ow)*36 + q*8;
  }
  const unsigned short* bp[8];
  #pragma unroll
  for (int cg=0;cg<8;cg++) bp[cg] = wb + (cw*128 + cg*16 + l16)*2304 + q*8;

  for (int cc = 0; cc < 256; cc += 32){
    if (cc) __syncthreads();
    #pragma unroll
    for (int it=0; it<6; it++){
      int idx = it*256 + t;
      if (idx < 1296){
        int cell = idx>>2, ci0 = (idx&3)<<3;
        int img = cell/81, c2 = cell - img*81;
        int tih = c2/9, tiw = c2 - tih*9;
        int ih = tih - 1, iw = tiw - 1;
        uint4 v = {0u,0u,0u,0u};
        if ((unsigned)ih < 8u && (unsigned)iw < 8u)
          v = *(const uint4*)&fin[((((n0+img)*8+ih)*8 + iw)<<8) + cc + ci0];
        *(uint2*)&tile[cell*36+ci0]   = make_uint2(v.x, v.y);
        *(uint2*)&tile[cell*36+ci0+4] = make_uint2(v.z, v.w);
      }
    }
    __syncthreads();
    for (int tap=0; tap<9; tap++){
      int kh = tap/3, kw = tap - kh*3;
      int aoff = (kh*9+kw)*36;
      short8v a[2], b[8];
      #pragma unroll
      for (int rg=0;rg<2;rg++) a[rg] = ld_frag(&tile[abase[rg]+aoff]);
      #pragma unroll
      for (int cg=0;cg<8;cg++) b[cg] = *(const short8v*)&bp[cg][tap*256+cc];
      #pragma unroll
      for (int rg=0;rg<2;rg++)
        #pragma unroll
        for (int cg=0;cg<8;cg++)
          acc[rg][cg] = __builtin_amdgcn_mfma_f32_16x16x32_bf16(a[rg], b[cg], acc[rg][cg], 0,0,0);
    }
  }
  #pragma unroll
  for (int rg=0;rg<2;rg++){
    int nimg = n0 + rw*2 + rg;
    #pragma unroll
    for (int cg=0;cg<8;cg++){
      int colg = cw*128 + cg*16 + l16;
      float s=0.f, qq=0.f;
      #pragma unroll
      for (int e=0;e<4;e++){ float xv = acc[rg][cg][e]; s += xv; qq += xv*xv; }
      s  += __shfl_xor(s,16,64);  s  += __shfl_xor(s,32,64);
      qq += __shfl_xor(qq,16,64); qq += __shfl_xor(qq,32,64);
      float mu = s*(1.f/16.f), var = qq*(1.f/16.f) - mu*mu;
      float gmv = rsqrtf(var+EPSF)*g[colg];
      float btv = be[colg] - mu*gmv;
      #pragma unroll
      for (int e=0;e<4;e++){
        int px = q*4 + e;
        float vv = lrelu(acc[rg][cg][e]*gmv+btv);
        feat [(nimg<<12) + (colg<<4) + px] = vv;
        featb[(nimg<<12) + (colg<<4) + px] = cvt_bf16(vv);
      }
    }
  }
}

// ---- gemmM MFMA: Cp[z] = featb(256x4096 bf16) @ T(4096x3200 fp32->bf16), ksplit 4x1024.
__global__ __launch_bounds__(256) void gemmM_k(const unsigned short* __restrict__ A,
                                               const float* __restrict__ T,
                                               float* __restrict__ Cp){
  const int t = threadIdx.x;
  const int n0 = blockIdx.x<<7, b0 = blockIdx.y<<7, k0 = blockIdx.z<<10;
  const int w = t>>6, lane = t&63, q = lane>>4, l16 = lane&15;
  const int rw = w&1, cw = w>>1;
  __shared__ unsigned short Asm[128*40];
  __shared__ unsigned short Bsm[128*40];
  floatx4 acc[4][4];
  #pragma unroll
  for (int mt=0;mt<4;mt++)
    #pragma unroll
    for (int nt=0;nt<4;nt++) acc[mt][nt] = (floatx4){0.f,0.f,0.f,0.f};
  for (int kk=0; kk<1024; kk+=32){
    if (kk) __syncthreads();
    #pragma unroll
    for (int m=0;m<2;m++){
      int idx = t + (m<<8);
      int row = idx>>2, seg = idx&3;
      uint4 v = *(const uint4*)&A[(b0+row)*4096 + k0 + kk + (seg<<3)];
      *(uint4*)&Asm[row*40 + (seg<<3)] = v;
    }
    #pragma unroll
    for (int m=0;m<4;m++){
      int idx = t + (m<<8);
      int kr = idx>>5, ns = (idx&31)<<2;
      float4 v = *(const float4*)&T[(k0+kk+kr)*3200 + n0 + ns];
      Bsm[(ns+0)*40 + kr] = cvt_bf16(v.x);
      Bsm[(ns+1)*40 + kr] = cvt_bf16(v.y);
      Bsm[(ns+2)*40 + kr] = cvt_bf16(v.z);
      Bsm[(ns+3)*40 + kr] = cvt_bf16(v.w);
    }
    __syncthreads();
    short8v af[4], bfr[4];
    #pragma unroll
    for (int mt=0;mt<4;mt++) af[mt] = *(const short8v*)&Asm[((rw<<6)+(mt<<4)+l16)*40 + (q<<3)];
    #pragma unroll
    for (int nt=0;nt<4;nt++) bfr[nt] = *(const short8v*)&Bsm[((cw<<6)+(nt<<4)+l16)*40 + (q<<3)];
    #pragma unroll
    for (int mt=0;mt<4;mt++)
      #pragma unroll
      for (int nt=0;nt<4;nt++)
        acc[mt][nt] = __builtin_amdgcn_mfma_f32_16x16x32_bf16(af[mt], bfr[nt], acc[mt][nt], 0,0,0);
  }
  float* C = Cp + blockIdx.z * 819200;
  #pragma unroll
  for (int mt=0;mt<4;mt++)
    #pragma unroll
    for (int nt=0;nt<4;nt++)
      #pragma unroll
      for (int e=0;e<4;e++){
        int row = b0 + (rw<<6) + (mt<<4) + (q<<2) + e;
        int col = n0 + (cw<<6) + (nt<<4) + l16;
        C[row*3200 + col] = acc[mt][nt][e];
      }
}

// reduce 4 partials -> Mh f16, rows padded [i][o][52] (pad = 0)
__global__ __launch_bounds__(256) void reduceM_k(const float* __restrict__ Cp, __half* __restrict__ Mh){
  int idx = blockIdx.x*256 + threadIdx.x;
  if (idx >= 851968) return;
  int i = idx / 3328, r = idx - i*3328;
  int o = r / 52, k = r - o*52;
  float v = 0.f;
  if (k < 50){
    int src = i*3200 + o*50 + k;
    v = Cp[src] + Cp[819200+src] + Cp[1638400+src] + Cp[2457600+src];
  }
  Mh[idx] = __float2half(v);
}

// ---- pairwise via packed f16: o_b[j,o] = sum_i exp(-sum_k |M[i,o,k]-M[j,o,k]|) - 1
__global__ __launch_bounds__(256) void pair_k(const __half* __restrict__ Mh,
                                              float* __restrict__ ob, unsigned short* __restrict__ obb){
  const int j = blockIdx.x, t = threadIdx.x;
  __shared__ __half2 Mj[1664];   // 64 o x 26 half2
  __shared__ float red[256];
  for (int k=t; k<1664; k+=256) Mj[k] = *(const __half2*)&Mh[j*3328 + (k<<1)];
  __syncthreads();
  const int o = t & 63, ss = t >> 6;
  const __half2* mjp = &Mj[o*26];
  float sum = 0.f;
  for (int i = ss<<6; i < (ss<<6)+64; i++){
    const __half2* mip = (const __half2*)&Mh[i*3328 + o*52];
    __half2 acch = __float2half2_rn(0.f);
    #pragma unroll
    for (int k2=0;k2<26;k2++){
      __half2 d = __hsub2(mip[k2], mjp[k2]);
      acch = __hadd2(acch, __habs2(d));
    }
    float dsum = __low2float(acch) + __high2float(acch);
    sum += __expf(-dsum);
  }
  red[(o<<2)+ss] = sum;
  __syncthreads();
  if (t < 64){
    float v = red[t<<2] + red[(t<<2)+1] + red[(t<<2)+2] + red[(t<<2)+3] - 1.0f;
    ob[(j<<6)+t] = v;
    obb[(j<<6)+t] = cvt_bf16(v);
  }
}

// ---- gemmFC MFMA: yp[z] = mb(256x4160 bf16) @ fcw(1000x4160 fp32->bf16)^T, ksplit 13x320.
__global__ __launch_bounds__(256) void gemmFC_k(const unsigned short* __restrict__ featb,
                                                const unsigned short* __restrict__ obb,
                                                const float* __restrict__ W, float* __restrict__ Cp){
  const int t = threadIdx.x;
  const int o0 = blockIdx.x<<7, b0 = blockIdx.y<<7, k0 = blockIdx.z*320;
  const int w = t>>6, lane = t&63, q = lane>>4, l16 = lane&15;
  const int rw = w&1, cw = w>>1;
  __shared__ unsigned short Asm[128*40];
  __shared__ unsigned short Bsm[128*40];
  floatx4 acc[4][4];
  #pragma unroll
  for (int mt=0;mt<4;mt++)
    #pragma unroll
    for (int nt=0;nt<4;nt++) acc[mt][nt] = (floatx4){0.f,0.f,0.f,0.f};
  for (int kk=0; kk<320; kk+=32){
    if (kk) __syncthreads();
    #pragma unroll
    for (int m=0;m<2;m++){
      int idx = t + (m<<8);
      int row = idx>>2, seg = idx&3;
      int i = k0 + kk + (seg<<3);
      uint4 v;
      if (i < 4096) v = *(const uint4*)&featb[(b0+row)*4096 + i];
      else          v = *(const uint4*)&obb[(b0+row)*64 + (i-4096)];
      *(uint4*)&Asm[row*40 + (seg<<3)] = v;
    }
    #pragma unroll
    for (int m=0;m<4;m++){
      int idx = t + (m<<8);
      int orow = idx>>3, seg = idx&7;
      int oo = o0 + orow;
      float4 v = {0,0,0,0};
      if (oo < 1000) v = *(const float4*)&W[oo*4160 + k0 + kk + (seg<<2)];
      unsigned short h[4] = {cvt_bf16(v.x), cvt_bf16(v.y), cvt_bf16(v.z), cvt_bf16(v.w)};
      *(uint2*)&Bsm[orow*40 + (seg<<2)] = *(uint2*)h;
    }
    __syncthreads();
    short8v af[4], bfr[4];
    #pragma unroll
    for (int mt=0;mt<4;mt++) af[mt] = *(const short8v*)&Asm[((rw<<6)+(mt<<4)+l16)*40 + (q<<3)];
    #pragma unroll
    for (int nt=0;nt<4;nt++) bfr[nt] = *(const short8v*)&Bsm[((cw<<6)+(nt<<4)+l16)*40 + (q<<3)];
    #pragma unroll
    for (int mt=0;mt<4;mt++)
      #pragma unroll
      for (int nt=0;nt<4;nt++)
        acc[mt][nt] = __builtin_amdgcn_mfma_f32_16x16x32_bf16(af[mt], bfr[nt], acc[mt][nt], 0,0,0);
  }
  float* C = Cp + blockIdx.z * 256000;
  #pragma unroll
  for (int mt=0;mt<4;mt++)
    #pragma unroll
    for (int nt=0;nt<4;nt++)
      #pragma unroll
      for (int e=0;e<4;e++){
        int row = b0 + (rw<<6) + (mt<<4) + (q<<2) + e;
        int col = o0 + (cw<<6) + (nt<<4) + l16;
        if (col < 1000) C[row*1000 + col] = acc[mt][nt][e];
      }
}

__global__ __launch_bounds__(256) void reduceY_k(const float* __restrict__ Cp, const float* __restrict__ bias,
                                                 float* __restrict__ y){
  int idx = blockIdx.x * 256 + threadIdx.x;
  if (idx >= 256000) return;
  int o = idx % 1000;
  float r = bias[o];
  #pragma unroll
  for (int s = 0; s < 13; s++) r += Cp[s*256000 + idx];
  y[idx] = r;
}

extern "C" void kernel_launch(void* const* d_in, const int* in_sizes, int n_in,
                              void* d_out, int out_size, void* d_ws, size_t ws_size,
                              hipStream_t stream){
  const float* x   = (const float*)d_in[0];
  const float* w1  = (const float*)d_in[1];
  const float* g1  = (const float*)d_in[3];
  const float* be1 = (const float*)d_in[4];
  const float* w2  = (const float*)d_in[5];
  const float* g2  = (const float*)d_in[7];
  const float* be2 = (const float*)d_in[8];
  const float* w3  = (const float*)d_in[9];
  const float* g3  = (const float*)d_in[11];
  const float* be3 = (const float*)d_in[12];
  const float* w4  = (const float*)d_in[13];
  const float* g4  = (const float*)d_in[15];
  const float* be4 = (const float*)d_in[16];
  const float* T   = (const float*)d_in[17];
  const float* fcw = (const float*)d_in[18];
  const float* fcb = (const float*)d_in[19];
  float* out = (float*)d_out;
  float* ws  = (float*)d_ws;

  // workspace (float units)
  unsigned short* f1raw = (unsigned short*)ws;               // 16,777,216 bf16
  unsigned short* f2    = (unsigned short*)(ws + 8388608);   //  8,388,608 bf16
  unsigned short* f3    = (unsigned short*)(ws + 12582912);  //  4,194,304 bf16
  unsigned short* featb = (unsigned short*)(ws + 14680064);  //  1,048,576 bf16
  unsigned short* wb1   = (unsigned short*)(ws + 15204352);  //      8,192 bf16
  unsigned short* wb2   = (unsigned short*)(ws + 15208448);  //    204,800 bf16
  unsigned short* wb3   = (unsigned short*)(ws + 15310848);  //    819,200 bf16
  unsigned short* wb4   = (unsigned short*)(ws + 15720448);  //    589,824 bf16
  float* gmbt1 = ws + 16015360;                              //     32,768
  float* S2    = ws + 16048128;                              //     32,768
  float* Q2    = ws + 16080896;                              //     32,768  (end 16,113,664 fl = 64.5 MB)
  // gemm-phase aliases over dead f1raw region (8,388,608 fl)
  float* Mp    = ws;                                         //  3,276,800
  __half* Mh   = (__half*)(ws + 3276800);                    //    851,968 f16 (425,984 fl)
  float* obuf  = ws + 3702784;                               //     16,384
  unsigned short* obb = (unsigned short*)(ws + 3719168);     //     16,384 bf16
  float* yp    = ws + 3727360;                               //  3,328,000 (end 7,055,360 < 8,388,608 OK)
  float* feat  = out;
  float* y     = out + 1048576;

  zero_k  <<<dim3(256),  256, 0, stream>>>(S2, 65536);       // S2+Q2 contiguous
  wprep1_k<<<dim3(32),   256, 0, stream>>>(w1, wb1);
  wprep_k <<<dim3(800),  256, 0, stream>>>(w2, wb2, 128, 64, 25);
  wprep_k <<<dim3(3200), 256, 0, stream>>>(w3, wb3, 256, 128, 25);
  wprep_k <<<dim3(2304), 256, 0, stream>>>(w4, wb4, 256, 256, 9);

  conv1_k<<<dim3(256),    256, 0, stream>>>(x, wb1, g1, be1, f1raw, gmbt1);
  conv2_k<<<dim3(2, 256), 256, 0, stream>>>(f1raw, wb2, gmbt1, S2, Q2, f2);
  conv3_k<<<dim3(256),    256, 0, stream>>>(f2, wb3, S2, Q2, g2, be2, g3, be3, f3);
  conv4_k<<<dim3(64),     256, 0, stream>>>(f3, wb4, g4, be4, feat, featb);

  gemmM_k  <<<dim3(25, 2, 4),  256, 0, stream>>>(featb, T, Mp);
  reduceM_k<<<dim3(3328),      256, 0, stream>>>(Mp, Mh);
  pair_k   <<<dim3(256),       256, 0, stream>>>(Mh, obuf, obb);
  gemmFC_k <<<dim3(8, 2, 13),  256, 0, stream>>>(featb, obb, fcw, yp);
  reduceY_k<<<dim3(1000),      256, 0, stream>>>(yp, fcb, y);
}

// Round 4
// 457.086 us; speedup vs baseline: 3.3252x; 1.3043x over previous
//
#include <hip/hip_runtime.h>
#include <hip/hip_fp16.h>
#include <math.h>

#define EPSF 1e-5f

typedef __attribute__((ext_vector_type(4))) float  floatx4;
typedef __attribute__((ext_vector_type(4))) short  short4v;
typedef __attribute__((ext_vector_type(8))) short  short8v;

__device__ __forceinline__ unsigned short cvt_bf16(float f){
  unsigned u = __float_as_uint(f);
  unsigned r = (u + 0x7FFFu + ((u >> 16) & 1u)) >> 16;
  return (unsigned short)r;
}
__device__ __forceinline__ float bf2f(unsigned short h){
  return __uint_as_float(((unsigned)h) << 16);
}
__device__ __forceinline__ short8v ld_frag(const unsigned short* p){
  short4v lo = *(const short4v*)p;
  short4v hi = *(const short4v*)(p + 4);
  return __builtin_shufflevector(lo, hi, 0,1,2,3,4,5,6,7);
}
__device__ __forceinline__ float lrelu(float x){ return x >= 0.f ? x : 0.2f*x; }

// ---- merged prep: wb1 | wb2 | wb3 | wb4 | zero S2/Q2  (one launch)
__global__ __launch_bounds__(256) void prep_k(const float* __restrict__ w1, const float* __restrict__ w2,
                                              const float* __restrict__ w3, const float* __restrict__ w4,
                                              unsigned short* __restrict__ wb1, unsigned short* __restrict__ wb2,
                                              unsigned short* __restrict__ wb3, unsigned short* __restrict__ wb4,
                                              float* __restrict__ SQ){
  int b = blockIdx.x, t = threadIdx.x;
  if (b < 32){                       // conv1: w[co][ci][5][5] -> wb1[co][128], k=(kh*6+kw)*4+ci
    int idx = b*256 + t;
    int co = idx >> 7, k = idx & 127;
    int tap6 = k >> 2, ci = k & 3;
    int kh = tap6 / 6, kw = tap6 - kh*6;
    float v = 0.f;
    if (ci < 3 && kw < 5 && kh < 5) v = w1[(co*3 + ci)*25 + kh*5 + kw];
    wb1[idx] = cvt_bf16(v);
  } else if (b < 832){               // conv2: [128co][25tap][64ci]
    int idx = (b-32)*256 + t;
    int co = idx / 1600, r = idx - co*1600;
    int tap = r >> 6, ci = r & 63;
    wb2[idx] = cvt_bf16(w2[(co*64 + ci)*25 + tap]);
  } else if (b < 4032){              // conv3: [256co][25tap][128ci]
    int idx = (b-832)*256 + t;
    int co = idx / 3200, r = idx - co*3200;
    int tap = r >> 7, ci = r & 127;
    wb3[idx] = cvt_bf16(w3[(co*128 + ci)*25 + tap]);
  } else if (b < 6336){              // conv4: [256co][9tap][256ci]
    int idx = (b-4032)*256 + t;
    int co = idx / 2304, r = idx - co*2304;
    int tap = r >> 8, ci = r & 255;
    wb4[idx] = cvt_bf16(w4[(co*256 + ci)*9 + tap]);
  } else {                           // zero S2+Q2 (65536 floats)
    int idx = (b-6336)*256 + t;
    SQ[idx] = 0.f;
  }
}

// ---- conv1 MFMA: x(256,3,64,64) fp32 -> f1raw NHWC bf16 (pre-norm) + gmbt1 per (n,co).
__global__ __launch_bounds__(256) void conv1_k(const float* __restrict__ x, const unsigned short* __restrict__ wb1,
                                               const float* __restrict__ g, const float* __restrict__ be,
                                               unsigned short* __restrict__ f1raw, float* __restrict__ gmbt1){
  const int t = threadIdx.x, n = blockIdx.x;
  const int w = t>>6, lane = t&63, q = lane>>4, l16 = lane&15;
  __shared__ unsigned short img[68*68*4];
  __shared__ float SQ[2][4][64];
  short8v bf[4][4];
  #pragma unroll
  for (int nt=0; nt<4; nt++)
    #pragma unroll
    for (int ks=0; ks<4; ks++)
      bf[nt][ks] = *(const short8v*)&wb1[(nt*16+l16)*128 + ks*32 + q*8];
  for (int i=t; i<9248; i+=256) ((unsigned*)img)[i] = 0u;
  __syncthreads();
  for (int idx=t; idx<3072; idx+=256){
    int ci = idx>>10, rem = idx&1023, ih = rem>>4, iw4 = (rem&15)<<2;
    float4 v = *(const float4*)&x[((n*3+ci)<<12) + (ih<<6) + iw4];
    int base = ((ih+2)*68 + (iw4+2))*4 + ci;
    img[base]    = cvt_bf16(v.x);
    img[base+4]  = cvt_bf16(v.y);
    img[base+8]  = cvt_bf16(v.z);
    img[base+12] = cvt_bf16(v.w);
  }
  __syncthreads();
  float sreg[4] = {0,0,0,0}, qreg[4] = {0,0,0,0};
  #pragma unroll
  for (int grp=0; grp<2; grp++){
    floatx4 acc[8][4];
    #pragma unroll
    for (int mi=0;mi<8;mi++)
      #pragma unroll
      for (int nt=0;nt<4;nt++) acc[mi][nt] = (floatx4){0.f,0.f,0.f,0.f};
    #pragma unroll
    for (int mi=0; mi<8; mi++){
      int mt = w*16 + grp*8 + mi;
      int oh = mt>>1, ow = ((mt&1)<<4) + l16;
      #pragma unroll
      for (int ks=0; ks<4; ks++){
        int t0 = ks*8 + 2*q;
        int kh = t0/6, kw = t0 - kh*6;
        short8v a = ld_frag(&img[((oh*2+kh)*68 + (ow*2+kw))*4]);
        #pragma unroll
        for (int nt=0; nt<4; nt++)
          acc[mi][nt] = __builtin_amdgcn_mfma_f32_16x16x32_bf16(a, bf[nt][ks], acc[mi][nt], 0,0,0);
      }
    }
    #pragma unroll
    for (int mi=0;mi<8;mi++){
      int mt = w*16 + grp*8 + mi;
      #pragma unroll
      for (int nt=0;nt<4;nt++)
        #pragma unroll
        for (int e=0;e<4;e++){
          float v = acc[mi][nt][e];
          sreg[nt] += v; qreg[nt] += v*v;
          int px = (mt<<4) + (q<<2) + e;
          f1raw[(((n<<10)+px)<<6) + (nt<<4) + l16] = cvt_bf16(v);
        }
    }
  }
  #pragma unroll
  for (int nt=0;nt<4;nt++){
    float s = sreg[nt], qq = qreg[nt];
    s  += __shfl_xor(s,16,64);  s  += __shfl_xor(s,32,64);
    qq += __shfl_xor(qq,16,64); qq += __shfl_xor(qq,32,64);
    if (q==0){ SQ[0][w][(nt<<4)+l16] = s; SQ[1][w][(nt<<4)+l16] = qq; }
  }
  __syncthreads();
  if (t < 64){
    float S = SQ[0][0][t]+SQ[0][1][t]+SQ[0][2][t]+SQ[0][3][t];
    float Q = SQ[1][0][t]+SQ[1][1][t]+SQ[1][2][t]+SQ[1][3][t];
    float mu = S*(1.f/1024.f), var = Q*(1.f/1024.f)-mu*mu;
    float gm = g[t]*rsqrtf(var+EPSF);
    gmbt1[((n<<6)+t)*2]   = gm;
    gmbt1[((n<<6)+t)*2+1] = be[t] - mu*gm;
  }
}

// ---- conv2: Mb=128 (half image) x Nb=64 co, grid (512, 2) -> 1024 blocks, ~2/CU.
// Cells stride 40 -> single ds_read_b128 a-frags; b double-buffered in regs; stats via atomics.
__global__ __launch_bounds__(256) void conv2_k(const unsigned short* __restrict__ fin,
                                               const unsigned short* __restrict__ wb,
                                               const float* __restrict__ gmbt1,
                                               float* __restrict__ S2, float* __restrict__ Q2,
                                               unsigned short* __restrict__ fout){
  const int t = threadIdx.x;
  const int n = blockIdx.x >> 1, half = blockIdx.x & 1;
  const int co0 = blockIdx.y << 6;
  const int w = t>>6, lane = t&63, q = lane>>4, l16 = lane&15;
  const int rw = w&1, cw = w>>1;
  __shared__ unsigned short tile[684*40];   // 19x36 cells x 40 -> 54.7 KB
  __shared__ float gmA[64], btA[64];
  if (t < 64){ gmA[t] = gmbt1[((n<<6)+t)*2]; btA[t] = gmbt1[((n<<6)+t)*2+1]; }
  __syncthreads();
  floatx4 acc[4][2];
  #pragma unroll
  for (int mt=0;mt<4;mt++)
    #pragma unroll
    for (int nt=0;nt<2;nt++) acc[mt][nt] = (floatx4){0.f,0.f,0.f,0.f};
  int cellb[4];
  #pragma unroll
  for (int mt=0;mt<4;mt++){
    int r = rw*64 + mt*16 + l16;
    int ohl = r>>4, ow = r&15;
    cellb[mt] = (2*ohl)*36 + 2*ow;
  }
  const unsigned short* bp[2];
  #pragma unroll
  for (int nt=0;nt<2;nt++) bp[nt] = wb + (co0 + cw*32 + nt*16 + l16)*1600 + q*8;

  for (int cc = 0; cc < 64; cc += 32){
    if (cc) __syncthreads();
    #pragma unroll
    for (int it=0; it<11; it++){
      int idx = it*256 + t;
      if (idx < 2736){
        int cell = idx>>2, ci0 = (idx&3)<<3;
        int tih = cell/36, tiw = cell - tih*36;
        int ih = half*16 + tih - 2, iw = tiw - 2;
        uint4 v = {0u,0u,0u,0u};
        if ((unsigned)ih < 32u && (unsigned)iw < 32u){
          v = *(const uint4*)&fin[(((n*32+ih)*32 + iw)<<6) + cc + ci0];
          unsigned short* hp = (unsigned short*)&v;
          #pragma unroll
          for (int jj=0;jj<8;jj++){
            int c = cc + ci0 + jj;
            hp[jj] = cvt_bf16(lrelu(bf2f(hp[jj])*gmA[c]+btA[c]));
          }
        }
        *(uint4*)&tile[cell*40 + ci0] = v;
      }
    }
    __syncthreads();
    short8v bcur[2];
    #pragma unroll
    for (int nt=0;nt<2;nt++) bcur[nt] = *(const short8v*)&bp[nt][cc];
    for (int tap=0; tap<25; tap++){
      int tn = tap+1 < 25 ? tap+1 : tap;
      short8v bnx[2];
      #pragma unroll
      for (int nt=0;nt<2;nt++) bnx[nt] = *(const short8v*)&bp[nt][tn*64+cc];
      int kh = tap/5, kw = tap - kh*5;
      int aoff = kh*36 + kw;
      short8v a[4];
      #pragma unroll
      for (int mt=0;mt<4;mt++) a[mt] = *(const short8v*)&tile[(cellb[mt]+aoff)*40 + q*8];
      #pragma unroll
      for (int mt=0;mt<4;mt++)
        #pragma unroll
        for (int nt=0;nt<2;nt++)
          acc[mt][nt] = __builtin_amdgcn_mfma_f32_16x16x32_bf16(a[mt], bcur[nt], acc[mt][nt], 0,0,0);
      bcur[0] = bnx[0]; bcur[1] = bnx[1];
    }
  }
  #pragma unroll
  for (int nt=0;nt<2;nt++){
    int co = co0 + cw*32 + nt*16 + l16;
    float s=0.f, qq=0.f;
    #pragma unroll
    for (int mt=0;mt<4;mt++)
      #pragma unroll
      for (int e=0;e<4;e++){ float xv = acc[mt][nt][e]; s += xv; qq += xv*xv; }
    s  += __shfl_xor(s,16,64);  s  += __shfl_xor(s,32,64);
    qq += __shfl_xor(qq,16,64); qq += __shfl_xor(qq,32,64);
    if (q == 0){
      atomicAdd(&S2[n*128 + co], s);
      atomicAdd(&Q2[n*128 + co], qq);
    }
    #pragma unroll
    for (int mt=0;mt<4;mt++)
      #pragma unroll
      for (int e=0;e<4;e++){
        int px = half*128 + rw*64 + mt*16 + q*4 + e;
        fout[((n<<8) + px)*128 + co] = cvt_bf16(acc[mt][nt][e]);
      }
  }
}

// ---- conv3: Mb=128 (2 images) x Nb=64 co, grid (128, 4) -> 512 blocks, 2/CU.
__global__ __launch_bounds__(256) void conv3_k(const unsigned short* __restrict__ fin,
                                               const unsigned short* __restrict__ wb,
                                               const float* __restrict__ S2, const float* __restrict__ Q2,
                                               const float* __restrict__ g2, const float* __restrict__ be2,
                                               const float* __restrict__ g, const float* __restrict__ be,
                                               unsigned short* __restrict__ fout){
  const int t = threadIdx.x;
  const int n0 = blockIdx.x << 1;
  const int co0 = blockIdx.y << 6;
  const int w = t>>6, lane = t&63, q = lane>>4, l16 = lane&15;
  const int rw = w&1, cw = w>>1;
  __shared__ unsigned short tile[2*361*40];   // 57.8 KB
  __shared__ float gmA[2][128], btA[2][128];
  {
    int ii = t>>7, c = t&127, nn = n0+ii;
    float S = S2[nn*128+c], Q = Q2[nn*128+c];
    float mu = S*(1.f/256.f), var = Q*(1.f/256.f) - mu*mu;
    float r = rsqrtf(var+EPSF)*g2[c];
    gmA[ii][c] = r; btA[ii][c] = be2[c] - mu*r;
  }
  __syncthreads();
  floatx4 acc[4][2];
  #pragma unroll
  for (int mt=0;mt<4;mt++)
    #pragma unroll
    for (int nt=0;nt<2;nt++) acc[mt][nt] = (floatx4){0.f,0.f,0.f,0.f};
  int cellb[4];
  #pragma unroll
  for (int mt=0;mt<4;mt++){
    int r = mt*16 + l16;
    int oh = r>>3, ow = r&7;
    cellb[mt] = (2*oh)*19 + 2*ow;
  }
  const unsigned short* bp[2];
  #pragma unroll
  for (int nt=0;nt<2;nt++) bp[nt] = wb + (co0 + cw*32 + nt*16 + l16)*3200 + q*8;

  for (int cc = 0; cc < 128; cc += 32){
    if (cc) __syncthreads();
    #pragma unroll
    for (int it=0; it<12; it++){
      int idx = it*256 + t;
      if (idx < 2888){
        int img = idx >= 1444 ? 1 : 0;
        int rem = idx - img*1444;
        int cell = rem>>2, ci0 = (rem&3)<<3;
        int tih = cell/19, tiw = cell - tih*19;
        int ih = tih - 2, iw = tiw - 2;
        uint4 v = {0u,0u,0u,0u};
        if ((unsigned)ih < 16u && (unsigned)iw < 16u){
          v = *(const uint4*)&fin[((((n0+img)*16+ih)*16 + iw)<<7) + cc + ci0];
          unsigned short* hp = (unsigned short*)&v;
          #pragma unroll
          for (int jj=0;jj<8;jj++){
            int c = cc + ci0 + jj;
            hp[jj] = cvt_bf16(lrelu(bf2f(hp[jj])*gmA[img][c]+btA[img][c]));
          }
        }
        *(uint4*)&tile[(img*361+cell)*40 + ci0] = v;
      }
    }
    __syncthreads();
    short8v bcur[2];
    #pragma unroll
    for (int nt=0;nt<2;nt++) bcur[nt] = *(const short8v*)&bp[nt][cc];
    for (int tap=0; tap<25; tap++){
      int tn = tap+1 < 25 ? tap+1 : tap;
      short8v bnx[2];
      #pragma unroll
      for (int nt=0;nt<2;nt++) bnx[nt] = *(const short8v*)&bp[nt][tn*128+cc];
      int kh = tap/5, kw = tap - kh*5;
      int aoff = kh*19 + kw;
      short8v a[4];
      #pragma unroll
      for (int mt=0;mt<4;mt++) a[mt] = *(const short8v*)&tile[(rw*361 + cellb[mt] + aoff)*40 + q*8];
      #pragma unroll
      for (int mt=0;mt<4;mt++)
        #pragma unroll
        for (int nt=0;nt<2;nt++)
          acc[mt][nt] = __builtin_amdgcn_mfma_f32_16x16x32_bf16(a[mt], bcur[nt], acc[mt][nt], 0,0,0);
      bcur[0] = bnx[0]; bcur[1] = bnx[1];
    }
  }
  const int nn = n0 + rw;
  #pragma unroll
  for (int nt=0;nt<2;nt++){
    int co = co0 + cw*32 + nt*16 + l16;
    float s=0.f, qq=0.f;
    #pragma unroll
    for (int mt=0;mt<4;mt++)
      #pragma unroll
      for (int e=0;e<4;e++){ float xv = acc[mt][nt][e]; s += xv; qq += xv*xv; }
    s  += __shfl_xor(s,16,64);  s  += __shfl_xor(s,32,64);
    qq += __shfl_xor(qq,16,64); qq += __shfl_xor(qq,32,64);
    float mu = s*(1.f/64.f), var = qq*(1.f/64.f) - mu*mu;
    float gmv = rsqrtf(var+EPSF)*g[co];
    float btv = be[co] - mu*gmv;
    #pragma unroll
    for (int mt=0;mt<4;mt++)
      #pragma unroll
      for (int e=0;e<4;e++){
        int row = mt*16 + q*4 + e;
        fout[((nn<<6) + row)*256 + co] = cvt_bf16(lrelu(acc[mt][nt][e]*gmv+btv));
      }
  }
}

// ---- conv4: Mb=32 (2 images) x Nb=64 co, grid (128, 4) -> 512 blocks.
__global__ __launch_bounds__(256) void conv4_k(const unsigned short* __restrict__ fin,
                                               const unsigned short* __restrict__ wb,
                                               const float* __restrict__ g, const float* __restrict__ be,
                                               float* __restrict__ feat, unsigned short* __restrict__ featb){
  const int t = threadIdx.x;
  const int n0 = blockIdx.x << 1;
  const int co0 = blockIdx.y << 6;
  const int w = t>>6, lane = t&63, q = lane>>4, l16 = lane&15;
  const int rw = w&1, cw = w>>1;
  __shared__ unsigned short tile[2*81*40];   // 13 KB
  floatx4 acc[2];
  acc[0] = (floatx4){0.f,0.f,0.f,0.f};
  acc[1] = (floatx4){0.f,0.f,0.f,0.f};
  const int oh = l16>>2, ow = l16&3;
  const int cellb = (2*oh)*9 + 2*ow;
  const unsigned short* bp[2];
  #pragma unroll
  for (int nt=0;nt<2;nt++) bp[nt] = wb + (co0 + cw*32 + nt*16 + l16)*2304 + q*8;

  for (int cc = 0; cc < 256; cc += 32){
    if (cc) __syncthreads();
    #pragma unroll
    for (int it=0; it<3; it++){
      int idx = it*256 + t;
      if (idx < 648){
        int img = idx >= 324 ? 1 : 0;
        int rem = idx - img*324;
        int cell = rem>>2, ci0 = (rem&3)<<3;
        int tih = cell/9, tiw = cell - tih*9;
        int ih = tih - 1, iw = tiw - 1;
        uint4 v = {0u,0u,0u,0u};
        if ((unsigned)ih < 8u && (unsigned)iw < 8u)
          v = *(const uint4*)&fin[((((n0+img)*8+ih)*8 + iw)<<8) + cc + ci0];
        *(uint4*)&tile[(img*81+cell)*40 + ci0] = v;
      }
    }
    __syncthreads();
    short8v bcur[2];
    #pragma unroll
    for (int nt=0;nt<2;nt++) bcur[nt] = *(const short8v*)&bp[nt][cc];
    for (int tap=0; tap<9; tap++){
      int tn = tap+1 < 9 ? tap+1 : tap;
      short8v bnx[2];
      #pragma unroll
      for (int nt=0;nt<2;nt++) bnx[nt] = *(const short8v*)&bp[nt][tn*256+cc];
      int kh = tap/3, kw = tap - kh*3;
      short8v a = *(const short8v*)&tile[(rw*81 + cellb + kh*9 + kw)*40 + q*8];
      #pragma unroll
      for (int nt=0;nt<2;nt++)
        acc[nt] = __builtin_amdgcn_mfma_f32_16x16x32_bf16(a, bcur[nt], acc[nt], 0,0,0);
      bcur[0] = bnx[0]; bcur[1] = bnx[1];
    }
  }
  const int nn = n0 + rw;
  #pragma unroll
  for (int nt=0;nt<2;nt++){
    int co = co0 + cw*32 + nt*16 + l16;
    float s=0.f, qq=0.f;
    #pragma unroll
    for (int e=0;e<4;e++){ float xv = acc[nt][e]; s += xv; qq += xv*xv; }
    s  += __shfl_xor(s,16,64);  s  += __shfl_xor(s,32,64);
    qq += __shfl_xor(qq,16,64); qq += __shfl_xor(qq,32,64);
    float mu = s*(1.f/16.f), var = qq*(1.f/16.f) - mu*mu;
    float gmv = rsqrtf(var+EPSF)*g[co];
    float btv = be[co] - mu*gmv;
    #pragma unroll
    for (int e=0;e<4;e++){
      int px = q*4 + e;
      float vv = lrelu(acc[nt][e]*gmv+btv);
      feat [(nn<<12) + (co<<4) + px] = vv;
      featb[(nn<<12) + (co<<4) + px] = cvt_bf16(vv);
    }
  }
}

// ---- gemmM MFMA: Cp[z] = featb(256x4096 bf16) @ T(4096x3200 fp32->bf16), ksplit 8x512.
__global__ __launch_bounds__(256) void gemmM_k(const unsigned short* __restrict__ A,
                                               const float* __restrict__ T,
                                               float* __restrict__ Cp){
  const int t = threadIdx.x;
  const int n0 = blockIdx.x<<7, b0 = blockIdx.y<<7, k0 = blockIdx.z<<9;
  const int w = t>>6, lane = t&63, q = lane>>4, l16 = lane&15;
  const int rw = w&1, cw = w>>1;
  __shared__ unsigned short Asm[128*40];
  __shared__ unsigned short Bsm[128*40];
  floatx4 acc[4][4];
  #pragma unroll
  for (int mt=0;mt<4;mt++)
    #pragma unroll
    for (int nt=0;nt<4;nt++) acc[mt][nt] = (floatx4){0.f,0.f,0.f,0.f};
  for (int kk=0; kk<512; kk+=32){
    if (kk) __syncthreads();
    #pragma unroll
    for (int m=0;m<2;m++){
      int idx = t + (m<<8);
      int row = idx>>2, seg = idx&3;
      uint4 v = *(const uint4*)&A[(b0+row)*4096 + k0 + kk + (seg<<3)];
      *(uint4*)&Asm[row*40 + (seg<<3)] = v;
    }
    #pragma unroll
    for (int m=0;m<4;m++){
      int idx = t + (m<<8);
      int kr = idx>>5, ns = (idx&31)<<2;
      float4 v = *(const float4*)&T[(k0+kk+kr)*3200 + n0 + ns];
      Bsm[(ns+0)*40 + kr] = cvt_bf16(v.x);
      Bsm[(ns+1)*40 + kr] = cvt_bf16(v.y);
      Bsm[(ns+2)*40 + kr] = cvt_bf16(v.z);
      Bsm[(ns+3)*40 + kr] = cvt_bf16(v.w);
    }
    __syncthreads();
    short8v af[4], bfr[4];
    #pragma unroll
    for (int mt=0;mt<4;mt++) af[mt] = *(const short8v*)&Asm[((rw<<6)+(mt<<4)+l16)*40 + (q<<3)];
    #pragma unroll
    for (int nt=0;nt<4;nt++) bfr[nt] = *(const short8v*)&Bsm[((cw<<6)+(nt<<4)+l16)*40 + (q<<3)];
    #pragma unroll
    for (int mt=0;mt<4;mt++)
      #pragma unroll
      for (int nt=0;nt<4;nt++)
        acc[mt][nt] = __builtin_amdgcn_mfma_f32_16x16x32_bf16(af[mt], bfr[nt], acc[mt][nt], 0,0,0);
  }
  float* C = Cp + blockIdx.z * 819200;
  #pragma unroll
  for (int mt=0;mt<4;mt++)
    #pragma unroll
    for (int nt=0;nt<4;nt++)
      #pragma unroll
      for (int e=0;e<4;e++){
        int row = b0 + (rw<<6) + (mt<<4) + (q<<2) + e;
        int col = n0 + (cw<<6) + (nt<<4) + l16;
        C[row*3200 + col] = acc[mt][nt][e];
      }
}

// reduce 8 partials -> Mh f16, rows padded [i][o][52] (pad = 0)
__global__ __launch_bounds__(256) void reduceM_k(const float* __restrict__ Cp, __half* __restrict__ Mh){
  int idx = blockIdx.x*256 + threadIdx.x;
  if (idx >= 851968) return;
  int i = idx / 3328, r = idx - i*3328;
  int o = r / 52, k = r - o*52;
  float v = 0.f;
  if (k < 50){
    int src = i*3200 + o*50 + k;
    #pragma unroll
    for (int s = 0; s < 8; s++) v += Cp[s*819200 + src];
  }
  Mh[idx] = __float2half(v);
}

// ---- pairwise via packed f16
__global__ __launch_bounds__(256) void pair_k(const __half* __restrict__ Mh,
                                              float* __restrict__ ob, unsigned short* __restrict__ obb){
  const int j = blockIdx.x, t = threadIdx.x;
  __shared__ __half2 Mj[1664];
  __shared__ float red[256];
  for (int k=t; k<1664; k+=256) Mj[k] = *(const __half2*)&Mh[j*3328 + (k<<1)];
  __syncthreads();
  const int o = t & 63, ss = t >> 6;
  const __half2* mjp = &Mj[o*26];
  float sum = 0.f;
  for (int i = ss<<6; i < (ss<<6)+64; i++){
    const __half2* mip = (const __half2*)&Mh[i*3328 + o*52];
    __half2 acch = __float2half2_rn(0.f);
    #pragma unroll
    for (int k2=0;k2<26;k2++){
      __half2 d = __hsub2(mip[k2], mjp[k2]);
      acch = __hadd2(acch, __habs2(d));
    }
    float dsum = __low2float(acch) + __high2float(acch);
    sum += __expf(-dsum);
  }
  red[(o<<2)+ss] = sum;
  __syncthreads();
  if (t < 64){
    float v = red[t<<2] + red[(t<<2)+1] + red[(t<<2)+2] + red[(t<<2)+3] - 1.0f;
    ob[(j<<6)+t] = v;
    obb[(j<<6)+t] = cvt_bf16(v);
  }
}

// ---- gemmFC MFMA: yp[z] = mb(256x4160 bf16) @ fcw(1000x4160 fp32->bf16)^T, ksplit 13x320.
__global__ __launch_bounds__(256) void gemmFC_k(const unsigned short* __restrict__ featb,
                                                const unsigned short* __restrict__ obb,
                                                const float* __restrict__ W, float* __restrict__ Cp){
  const int t = threadIdx.x;
  const int o0 = blockIdx.x<<7, b0 = blockIdx.y<<7, k0 = blockIdx.z*320;
  const int w = t>>6, lane = t&63, q = lane>>4, l16 = lane&15;
  const int rw = w&1, cw = w>>1;
  __shared__ unsigned short Asm[128*40];
  __shared__ unsigned short Bsm[128*40];
  floatx4 acc[4][4];
  #pragma unroll
  for (int mt=0;mt<4;mt++)
    #pragma unroll
    for (int nt=0;nt<4;nt++) acc[mt][nt] = (floatx4){0.f,0.f,0.f,0.f};
  for (int kk=0; kk<320; kk+=32){
    if (kk) __syncthreads();
    #pragma unroll
    for (int m=0;m<2;m++){
      int idx = t + (m<<8);
      int row = idx>>2, seg = idx&3;
      int i = k0 + kk + (seg<<3);
      uint4 v;
      if (i < 4096) v = *(const uint4*)&featb[(b0+row)*4096 + i];
      else          v = *(const uint4*)&obb[(b0+row)*64 + (i-4096)];
      *(uint4*)&Asm[row*40 + (seg<<3)] = v;
    }
    #pragma unroll
    for (int m=0;m<4;m++){
      int idx = t + (m<<8);
      int orow = idx>>3, seg = idx&7;
      int oo = o0 + orow;
      float4 v = {0,0,0,0};
      if (oo < 1000) v = *(const float4*)&W[oo*4160 + k0 + kk + (seg<<2)];
      unsigned short h[4] = {cvt_bf16(v.x), cvt_bf16(v.y), cvt_bf16(v.z), cvt_bf16(v.w)};
      *(uint2*)&Bsm[orow*40 + (seg<<2)] = *(uint2*)h;
    }
    __syncthreads();
    short8v af[4], bfr[4];
    #pragma unroll
    for (int mt=0;mt<4;mt++) af[mt] = *(const short8v*)&Asm[((rw<<6)+(mt<<4)+l16)*40 + (q<<3)];
    #pragma unroll
    for (int nt=0;nt<4;nt++) bfr[nt] = *(const short8v*)&Bsm[((cw<<6)+(nt<<4)+l16)*40 + (q<<3)];
    #pragma unroll
    for (int mt=0;mt<4;mt++)
      #pragma unroll
      for (int nt=0;nt<4;nt++)
        acc[mt][nt] = __builtin_amdgcn_mfma_f32_16x16x32_bf16(af[mt], bfr[nt], acc[mt][nt], 0,0,0);
  }
  float* C = Cp + blockIdx.z * 256000;
  #pragma unroll
  for (int mt=0;mt<4;mt++)
    #pragma unroll
    for (int nt=0;nt<4;nt++)
      #pragma unroll
      for (int e=0;e<4;e++){
        int row = b0 + (rw<<6) + (mt<<4) + (q<<2) + e;
        int col = o0 + (cw<<6) + (nt<<4) + l16;
        if (col < 1000) C[row*1000 + col] = acc[mt][nt][e];
      }
}

__global__ __launch_bounds__(256) void reduceY_k(const float* __restrict__ Cp, const float* __restrict__ bias,
                                                 float* __restrict__ y){
  int idx = blockIdx.x * 256 + threadIdx.x;
  if (idx >= 256000) return;
  int o = idx % 1000;
  float r = bias[o];
  #pragma unroll
  for (int s = 0; s < 13; s++) r += Cp[s*256000 + idx];
  y[idx] = r;
}

extern "C" void kernel_launch(void* const* d_in, const int* in_sizes, int n_in,
                              void* d_out, int out_size, void* d_ws, size_t ws_size,
                              hipStream_t stream){
  const float* x   = (const float*)d_in[0];
  const float* w1  = (const float*)d_in[1];
  const float* g1  = (const float*)d_in[3];
  const float* be1 = (const float*)d_in[4];
  const float* w2  = (const float*)d_in[5];
  const float* g2  = (const float*)d_in[7];
  const float* be2 = (const float*)d_in[8];
  const float* w3  = (const float*)d_in[9];
  const float* g3  = (const float*)d_in[11];
  const float* be3 = (const float*)d_in[12];
  const float* w4  = (const float*)d_in[13];
  const float* g4  = (const float*)d_in[15];
  const float* be4 = (const float*)d_in[16];
  const float* T   = (const float*)d_in[17];
  const float* fcw = (const float*)d_in[18];
  const float* fcb = (const float*)d_in[19];
  float* out = (float*)d_out;
  float* ws  = (float*)d_ws;

  // workspace (float units)
  unsigned short* f1raw = (unsigned short*)ws;               // @0        8,388,608 fl
  unsigned short* f2    = (unsigned short*)(ws + 8388608);   //           4,194,304 fl
  unsigned short* f3    = (unsigned short*)(ws + 12582912);  //           2,097,152 fl
  unsigned short* featb = (unsigned short*)(ws + 14680064);  //             524,288 fl
  unsigned short* wb1   = (unsigned short*)(ws + 15204352);  //               4,096 fl
  unsigned short* wb2   = (unsigned short*)(ws + 15208448);  //             102,400 fl
  unsigned short* wb3   = (unsigned short*)(ws + 15310848);  //             409,600 fl
  unsigned short* wb4   = (unsigned short*)(ws + 15720448);  //             294,912 fl
  float* gmbt1 = ws + 16015360;                              //              32,768
  float* S2    = ws + 16048128;                              //              32,768
  float* Q2    = ws + 16080896;                              //              32,768  (end 16,113,664)
  // gemm-phase region (after conv region; featb must survive)
  float* Mp    = ws + 16113664;                              //  6,553,600 (8 x 819,200)
  __half* Mh   = (__half*)(ws + 22667264);                   //    851,968 f16 (425,984 fl)
  float* obuf  = ws + 23093248;                              //     16,384
  unsigned short* obb = (unsigned short*)(ws + 23109632);    //     16,384 bf16 (8,192 fl)
  float* yp    = ws + 23117824;                              //  3,328,000 (end 26,445,824 fl = 105.8 MB)
  float* feat  = out;
  float* y     = out + 1048576;

  prep_k<<<dim3(6592), 256, 0, stream>>>(w1, w2, w3, w4, wb1, wb2, wb3, wb4, S2);

  conv1_k<<<dim3(256),     256, 0, stream>>>(x, wb1, g1, be1, f1raw, gmbt1);
  conv2_k<<<dim3(512, 2),  256, 0, stream>>>(f1raw, wb2, gmbt1, S2, Q2, f2);
  conv3_k<<<dim3(128, 4),  256, 0, stream>>>(f2, wb3, S2, Q2, g2, be2, g3, be3, f3);
  conv4_k<<<dim3(128, 4),  256, 0, stream>>>(f3, wb4, g4, be4, feat, featb);

  gemmM_k  <<<dim3(25, 2, 8),  256, 0, stream>>>(featb, T, Mp);
  reduceM_k<<<dim3(3328),      256, 0, stream>>>(Mp, Mh);
  pair_k   <<<dim3(256),       256, 0, stream>>>(Mh, obuf, obb);
  gemmFC_k <<<dim3(8, 2, 13),  256, 0, stream>>>(featb, obb, fcw, yp);
  reduceY_k<<<dim3(1000),      256, 0, stream>>>(yp, fcb, y);
}

// Round 5
// 367.932 us; speedup vs baseline: 4.1309x; 1.2423x over previous
//
#include <hip/hip_runtime.h>
#include <hip/hip_fp16.h>
#include <math.h>

#define EPSF 1e-5f

typedef __attribute__((ext_vector_type(4))) float  floatx4;
typedef __attribute__((ext_vector_type(4))) short  short4v;
typedef __attribute__((ext_vector_type(8))) short  short8v;

__device__ __forceinline__ unsigned short cvt_bf16(float f){
  unsigned u = __float_as_uint(f);
  unsigned r = (u + 0x7FFFu + ((u >> 16) & 1u)) >> 16;
  return (unsigned short)r;
}
__device__ __forceinline__ float bf2f(unsigned short h){
  return __uint_as_float(((unsigned)h) << 16);
}
__device__ __forceinline__ short8v ld_frag(const unsigned short* p){
  short4v lo = *(const short4v*)p;
  short4v hi = *(const short4v*)(p + 4);
  return __builtin_shufflevector(lo, hi, 0,1,2,3,4,5,6,7);
}
__device__ __forceinline__ float lrelu(float x){ return x >= 0.f ? x : 0.2f*x; }

// ---- merged prep. Weights fragment-packed: [co16grp][tap][ccgrp][lane64][8]
// b-frag lane mapping (16x16x32): co_local = lane&15, k = (lane>>4)*8 + j.
__global__ __launch_bounds__(256) void prep_k(const float* __restrict__ w1, const float* __restrict__ w2,
                                              const float* __restrict__ w3, const float* __restrict__ w4,
                                              unsigned short* __restrict__ wb1, unsigned short* __restrict__ wb2,
                                              unsigned short* __restrict__ wb3, unsigned short* __restrict__ wb4,
                                              float* __restrict__ SQ){
  int b = blockIdx.x, t = threadIdx.x;
  if (b < 32){                       // conv1: 4 grp x 4 ks x 512; k=(kh*6+kw)*4+ci over K=128
    int idx = b*256 + t;             // 8192 shorts
    int j = idx&7, lane = (idx>>3)&63, ks = (idx>>9)&3, grp = idx>>11;
    int co = grp*16 + (lane&15);
    int k = ks*32 + ((lane>>4)<<3) + j;
    int tap6 = k>>2, ci = k&3;
    int kh = tap6/6, kw = tap6 - kh*6;
    float v = 0.f;
    if (ci < 3 && kh < 5 && kw < 5) v = w1[(co*3 + ci)*25 + kh*5 + kw];
    wb1[idx] = cvt_bf16(v);
  } else if (b < 832){               // conv2: 8 grp x 25 tap x 2 ccg x 512 = 204800
    int idx = (b-32)*256 + t;
    int grp = idx/25600, rem = idx - grp*25600;
    int tap = rem/1024, rem2 = rem - tap*1024;
    int ccg = rem2>>9, lane = (rem2>>3)&63, j = rem2&7;
    int co = grp*16 + (lane&15);
    int ci = ccg*32 + ((lane>>4)<<3) + j;
    wb2[idx] = cvt_bf16(w2[(co*64 + ci)*25 + tap]);
  } else if (b < 4032){              // conv3: 16 grp x 25 tap x 4 ccg x 512 = 819200
    int idx = (b-832)*256 + t;
    int grp = idx/51200, rem = idx - grp*51200;
    int tap = rem/2048, rem2 = rem - tap*2048;
    int ccg = rem2>>9, lane = (rem2>>3)&63, j = rem2&7;
    int co = grp*16 + (lane&15);
    int ci = ccg*32 + ((lane>>4)<<3) + j;
    wb3[idx] = cvt_bf16(w3[(co*128 + ci)*25 + tap]);
  } else if (b < 6336){              // conv4: 16 grp x 9 tap x 8 ccg x 512 = 589824
    int idx = (b-4032)*256 + t;
    int grp = idx/36864, rem = idx - grp*36864;
    int tap = rem/4096, rem2 = rem - tap*4096;
    int ccg = rem2>>9, lane = (rem2>>3)&63, j = rem2&7;
    int co = grp*16 + (lane&15);
    int ci = ccg*32 + ((lane>>4)<<3) + j;
    wb4[idx] = cvt_bf16(w4[(co*256 + ci)*9 + tap]);
  } else {                           // zero S1/Q1/S2/Q2 (98304 floats)
    int idx = (b-6336)*256 + t;
    SQ[idx] = 0.f;
  }
}

// ---- conv1: half-image blocks (grid 512). Raw f1 + S1/Q1 atomics.
__global__ __launch_bounds__(256) void conv1_k(const float* __restrict__ x, const unsigned short* __restrict__ wb1P,
                                               float* __restrict__ S1, float* __restrict__ Q1,
                                               unsigned short* __restrict__ f1raw){
  const int t = threadIdx.x, n = blockIdx.x>>1, half = blockIdx.x&1;
  const int w = t>>6, lane = t&63, q = lane>>4, l16 = lane&15;
  __shared__ unsigned short img[35*68*4];   // [tih][iw+2][ci] 19 KB; ih = half*32-2+tih
  short8v bf[4][4];
  #pragma unroll
  for (int nt=0;nt<4;nt++)
    #pragma unroll
    for (int ks=0;ks<4;ks++)
      bf[nt][ks] = *(const short8v*)&wb1P[((nt*4+ks)*64 + lane)*8];
  for (int i=t; i<4760; i+=256) ((unsigned*)img)[i] = 0u;
  __syncthreads();
  for (int idx=t; idx<1680; idx+=256){
    int ci = idx/560, rem = idx - ci*560;
    int tih = rem>>4, iw4 = (rem&15)<<2;
    int ih = half*32 - 2 + tih;
    if ((unsigned)ih < 64u){
      float4 v = *(const float4*)&x[((n*3+ci)<<12) + (ih<<6) + iw4];
      int base = (tih*68 + iw4 + 2)*4 + ci;
      img[base]    = cvt_bf16(v.x);
      img[base+4]  = cvt_bf16(v.y);
      img[base+8]  = cvt_bf16(v.z);
      img[base+12] = cvt_bf16(v.w);
    }
  }
  __syncthreads();
  floatx4 acc[8][4];
  #pragma unroll
  for (int mi=0;mi<8;mi++)
    #pragma unroll
    for (int nt=0;nt<4;nt++) acc[mi][nt] = (floatx4){0.f,0.f,0.f,0.f};
  #pragma unroll
  for (int mi=0; mi<8; mi++){
    int r = w*8 + mi;                 // mtile 0..31 within half
    int ohl = r>>1, ow = ((r&1)<<4) + l16;
    #pragma unroll
    for (int ks=0; ks<4; ks++){
      int t0 = ks*8 + 2*q;
      int kh = t0/6, kw = t0 - kh*6;
      short8v a = ld_frag(&img[((ohl*2+kh)*68 + ow*2 + kw)*4]);
      #pragma unroll
      for (int nt=0; nt<4; nt++)
        acc[mi][nt] = __builtin_amdgcn_mfma_f32_16x16x32_bf16(a, bf[nt][ks], acc[mi][nt], 0,0,0);
    }
  }
  float sreg[4] = {0,0,0,0}, qreg[4] = {0,0,0,0};
  #pragma unroll
  for (int mi=0;mi<8;mi++){
    int r = w*8 + mi;
    #pragma unroll
    for (int nt=0;nt<4;nt++)
      #pragma unroll
      for (int e=0;e<4;e++){
        float v = acc[mi][nt][e];
        sreg[nt] += v; qreg[nt] += v*v;
        int px = half*512 + (r<<4) + (q<<2) + e;
        f1raw[(((n<<10)+px)<<6) + (nt<<4) + l16] = cvt_bf16(v);
      }
  }
  #pragma unroll
  for (int nt=0;nt<4;nt++){
    float s = sreg[nt], qq = qreg[nt];
    s  += __shfl_xor(s,16,64);  s  += __shfl_xor(s,32,64);
    qq += __shfl_xor(qq,16,64); qq += __shfl_xor(qq,32,64);
    if (q==0){
      atomicAdd(&S1[(n<<6) + (nt<<4) + l16], s);
      atomicAdd(&Q1[(n<<6) + (nt<<4) + l16], qq);
    }
  }
}

// ---- conv2: Mb=128 (half image) x Nb=128 (all co), grid 512 -> 2 blocks/CU.
__global__ __launch_bounds__(256) void conv2_k(const unsigned short* __restrict__ fin,
                                               const unsigned short* __restrict__ wbP,
                                               const float* __restrict__ S1, const float* __restrict__ Q1,
                                               const float* __restrict__ g1, const float* __restrict__ be1,
                                               float* __restrict__ S2, float* __restrict__ Q2,
                                               unsigned short* __restrict__ fout){
  const int t = threadIdx.x;
  const int n = blockIdx.x >> 1, half = blockIdx.x & 1;
  const int w = t>>6, lane = t&63, q = lane>>4, l16 = lane&15;
  const int rw = w&1, cw = w>>1;
  __shared__ unsigned short tile[684*40];   // 19x36 cells, 54.7 KB
  __shared__ float gmA[64], btA[64];
  if (t < 64){
    float S = S1[(n<<6)+t], Q = Q1[(n<<6)+t];
    float mu = S*(1.f/1024.f), var = Q*(1.f/1024.f) - mu*mu;
    float r = rsqrtf(var+EPSF)*g1[t];
    gmA[t] = r; btA[t] = be1[t] - mu*r;
  }
  __syncthreads();
  floatx4 acc[4][4];
  #pragma unroll
  for (int mt=0;mt<4;mt++)
    #pragma unroll
    for (int nt=0;nt<4;nt++) acc[mt][nt] = (floatx4){0.f,0.f,0.f,0.f};
  int cellb[4];
  #pragma unroll
  for (int mt=0;mt<4;mt++){
    int r = rw*64 + mt*16 + l16;
    int ohl = r>>4, ow = r&15;
    cellb[mt] = (2*ohl)*36 + 2*ow;
  }
  for (int ccg = 0; ccg < 2; ccg++){
    const int cc = ccg<<5;
    if (ccg) __syncthreads();
    #pragma unroll
    for (int it=0; it<11; it++){
      int idx = it*256 + t;
      if (idx < 2736){
        int cell = idx>>2, ci0 = (idx&3)<<3;
        int tih = cell/36, tiw = cell - tih*36;
        int ih = half*16 + tih - 2, iw = tiw - 2;
        uint4 v = {0u,0u,0u,0u};
        if ((unsigned)ih < 32u && (unsigned)iw < 32u){
          v = *(const uint4*)&fin[(((n*32+ih)*32 + iw)<<6) + cc + ci0];
          unsigned short* hp = (unsigned short*)&v;
          #pragma unroll
          for (int jj=0;jj<8;jj++){
            int c = cc + ci0 + jj;
            hp[jj] = cvt_bf16(lrelu(bf2f(hp[jj])*gmA[c]+btA[c]));
          }
        }
        *(uint4*)&tile[cell*40 + ci0] = v;
      }
    }
    __syncthreads();
    const unsigned short* bp[4];
    #pragma unroll
    for (int nt=0;nt<4;nt++)
      bp[nt] = wbP + ((((cw*4+nt)*25)*2 + ccg)<<9) + lane*8;   // +tap*1024
    short8v bcur[4];
    #pragma unroll
    for (int nt=0;nt<4;nt++) bcur[nt] = *(const short8v*)bp[nt];
    for (int tap=0; tap<25; tap++){
      int tn = tap+1 < 25 ? tap+1 : tap;
      short8v bnx[4];
      #pragma unroll
      for (int nt=0;nt<4;nt++) bnx[nt] = *(const short8v*)(bp[nt] + (tn<<10));
      int kh = tap/5, kw = tap - kh*5;
      int aoff = kh*36 + kw;
      short8v a[4];
      #pragma unroll
      for (int mt=0;mt<4;mt++) a[mt] = *(const short8v*)&tile[(cellb[mt]+aoff)*40 + q*8];
      #pragma unroll
      for (int mt=0;mt<4;mt++)
        #pragma unroll
        for (int nt=0;nt<4;nt++)
          acc[mt][nt] = __builtin_amdgcn_mfma_f32_16x16x32_bf16(a[mt], bcur[nt], acc[mt][nt], 0,0,0);
      #pragma unroll
      for (int nt=0;nt<4;nt++) bcur[nt] = bnx[nt];
    }
  }
  #pragma unroll
  for (int nt=0;nt<4;nt++){
    int co = cw*64 + nt*16 + l16;
    float s=0.f, qq=0.f;
    #pragma unroll
    for (int mt=0;mt<4;mt++)
      #pragma unroll
      for (int e=0;e<4;e++){ float xv = acc[mt][nt][e]; s += xv; qq += xv*xv; }
    s  += __shfl_xor(s,16,64);  s  += __shfl_xor(s,32,64);
    qq += __shfl_xor(qq,16,64); qq += __shfl_xor(qq,32,64);
    if (q == 0){
      atomicAdd(&S2[n*128 + co], s);
      atomicAdd(&Q2[n*128 + co], qq);
    }
    #pragma unroll
    for (int mt=0;mt<4;mt++)
      #pragma unroll
      for (int e=0;e<4;e++){
        int px = half*128 + rw*64 + mt*16 + q*4 + e;
        fout[((n<<8) + px)*128 + co] = cvt_bf16(acc[mt][nt][e]);
      }
  }
}

// ---- conv3: Mb=64 (1 image) x Nb=128, grid (256,2) -> 512 blocks. Fused IN3+lrelu.
__global__ __launch_bounds__(256) void conv3_k(const unsigned short* __restrict__ fin,
                                               const unsigned short* __restrict__ wbP,
                                               const float* __restrict__ S2, const float* __restrict__ Q2,
                                               const float* __restrict__ g2, const float* __restrict__ be2,
                                               const float* __restrict__ g, const float* __restrict__ be,
                                               unsigned short* __restrict__ fout){
  const int t = threadIdx.x, n = blockIdx.x, co0 = blockIdx.y<<7;
  const int w = t>>6, lane = t&63, q = lane>>4, l16 = lane&15;
  const int rw = w&1, cw = w>>1;
  __shared__ unsigned short tile[361*40];   // 28.9 KB
  __shared__ float gmA[128], btA[128];
  __shared__ float SQs[2][128], SQq[2][128];
  if (t < 128){
    float S = S2[n*128+t], Q = Q2[n*128+t];
    float mu = S*(1.f/256.f), var = Q*(1.f/256.f) - mu*mu;
    float r = rsqrtf(var+EPSF)*g2[t];
    gmA[t] = r; btA[t] = be2[t] - mu*r;
  }
  __syncthreads();
  floatx4 acc[2][4];
  #pragma unroll
  for (int mt=0;mt<2;mt++)
    #pragma unroll
    for (int nt=0;nt<4;nt++) acc[mt][nt] = (floatx4){0.f,0.f,0.f,0.f};
  int cellb[2];
  #pragma unroll
  for (int mt=0;mt<2;mt++){
    int r = rw*32 + mt*16 + l16;
    int oh = r>>3, ow = r&7;
    cellb[mt] = (2*oh)*19 + 2*ow;
  }
  for (int ccg = 0; ccg < 4; ccg++){
    const int cc = ccg<<5;
    if (ccg) __syncthreads();
    #pragma unroll
    for (int it=0; it<6; it++){
      int idx = it*256 + t;
      if (idx < 1444){
        int cell = idx>>2, ci0 = (idx&3)<<3;
        int tih = cell/19, tiw = cell - tih*19;
        int ih = tih - 2, iw = tiw - 2;
        uint4 v = {0u,0u,0u,0u};
        if ((unsigned)ih < 16u && (unsigned)iw < 16u){
          v = *(const uint4*)&fin[(((n*16+ih)*16 + iw)<<7) + cc + ci0];
          unsigned short* hp = (unsigned short*)&v;
          #pragma unroll
          for (int jj=0;jj<8;jj++){
            int c = cc + ci0 + jj;
            hp[jj] = cvt_bf16(lrelu(bf2f(hp[jj])*gmA[c]+btA[c]));
          }
        }
        *(uint4*)&tile[cell*40 + ci0] = v;
      }
    }
    __syncthreads();
    const unsigned short* bp[4];
    #pragma unroll
    for (int nt=0;nt<4;nt++)
      bp[nt] = wbP + (((((co0>>4)+cw*4+nt)*25)*4 + ccg)<<9) + lane*8;  // +tap*2048
    short8v bcur[4];
    #pragma unroll
    for (int nt=0;nt<4;nt++) bcur[nt] = *(const short8v*)bp[nt];
    for (int tap=0; tap<25; tap++){
      int tn = tap+1 < 25 ? tap+1 : tap;
      short8v bnx[4];
      #pragma unroll
      for (int nt=0;nt<4;nt++) bnx[nt] = *(const short8v*)(bp[nt] + (tn<<11));
      int kh = tap/5, kw = tap - kh*5;
      int aoff = kh*19 + kw;
      short8v a[2];
      #pragma unroll
      for (int mt=0;mt<2;mt++) a[mt] = *(const short8v*)&tile[(cellb[mt]+aoff)*40 + q*8];
      #pragma unroll
      for (int mt=0;mt<2;mt++)
        #pragma unroll
        for (int nt=0;nt<4;nt++)
          acc[mt][nt] = __builtin_amdgcn_mfma_f32_16x16x32_bf16(a[mt], bcur[nt], acc[mt][nt], 0,0,0);
      #pragma unroll
      for (int nt=0;nt<4;nt++) bcur[nt] = bnx[nt];
    }
  }
  #pragma unroll
  for (int nt=0;nt<4;nt++){
    int lcol = cw*64 + nt*16 + l16;
    float s=0.f, qq=0.f;
    #pragma unroll
    for (int mt=0;mt<2;mt++)
      #pragma unroll
      for (int e=0;e<4;e++){ float xv = acc[mt][nt][e]; s += xv; qq += xv*xv; }
    s  += __shfl_xor(s,16,64);  s  += __shfl_xor(s,32,64);
    qq += __shfl_xor(qq,16,64); qq += __shfl_xor(qq,32,64);
    if (q == 0){ SQs[rw][lcol] = s; SQq[rw][lcol] = qq; }
  }
  __syncthreads();
  #pragma unroll
  for (int nt=0;nt<4;nt++){
    int lcol = cw*64 + nt*16 + l16, co = co0 + lcol;
    float S = SQs[0][lcol] + SQs[1][lcol];
    float Q = SQq[0][lcol] + SQq[1][lcol];
    float mu = S*(1.f/64.f), var = Q*(1.f/64.f) - mu*mu;
    float gmv = rsqrtf(var+EPSF)*g[co];
    float btv = be[co] - mu*gmv;
    #pragma unroll
    for (int mt=0;mt<2;mt++)
      #pragma unroll
      for (int e=0;e<4;e++){
        int row = rw*32 + mt*16 + q*4 + e;
        fout[((n<<6) + row)*256 + co] = cvt_bf16(lrelu(acc[mt][nt][e]*gmv+btv));
      }
  }
}

// ---- conv4: Mb=32 (2 images) x Nb=64, grid (128,4). Fused IN4+lrelu -> feat + featb.
__global__ __launch_bounds__(256) void conv4_k(const unsigned short* __restrict__ fin,
                                               const unsigned short* __restrict__ wbP,
                                               const float* __restrict__ g, const float* __restrict__ be,
                                               float* __restrict__ feat, unsigned short* __restrict__ featb){
  const int t = threadIdx.x;
  const int n0 = blockIdx.x << 1, co0 = blockIdx.y << 6;
  const int w = t>>6, lane = t&63, q = lane>>4, l16 = lane&15;
  const int rw = w&1, cw = w>>1;
  __shared__ unsigned short tile[2*81*40];
  floatx4 acc[2];
  acc[0] = (floatx4){0.f,0.f,0.f,0.f};
  acc[1] = (floatx4){0.f,0.f,0.f,0.f};
  const int oh = l16>>2, ow = l16&3;
  const int cellb = (2*oh)*9 + 2*ow;
  for (int ccg = 0; ccg < 8; ccg++){
    const int cc = ccg<<5;
    if (ccg) __syncthreads();
    #pragma unroll
    for (int it=0; it<3; it++){
      int idx = it*256 + t;
      if (idx < 648){
        int img = idx >= 324 ? 1 : 0;
        int rem = idx - img*324;
        int cell = rem>>2, ci0 = (rem&3)<<3;
        int tih = cell/9, tiw = cell - tih*9;
        int ih = tih - 1, iw = tiw - 1;
        uint4 v = {0u,0u,0u,0u};
        if ((unsigned)ih < 8u && (unsigned)iw < 8u)
          v = *(const uint4*)&fin[((((n0+img)*8+ih)*8 + iw)<<8) + cc + ci0];
        *(uint4*)&tile[(img*81+cell)*40 + ci0] = v;
      }
    }
    __syncthreads();
    const unsigned short* bp[2];
    #pragma unroll
    for (int nt=0;nt<2;nt++)
      bp[nt] = wbP + (((((co0>>4)+cw*2+nt)*9)*8 + ccg)<<9) + lane*8;  // +tap*4096
    short8v bcur[2];
    #pragma unroll
    for (int nt=0;nt<2;nt++) bcur[nt] = *(const short8v*)bp[nt];
    for (int tap=0; tap<9; tap++){
      int tn = tap+1 < 9 ? tap+1 : tap;
      short8v bnx[2];
      #pragma unroll
      for (int nt=0;nt<2;nt++) bnx[nt] = *(const short8v*)(bp[nt] + (tn<<12));
      int kh = tap/3, kw = tap - kh*3;
      short8v a = *(const short8v*)&tile[(rw*81 + cellb + kh*9 + kw)*40 + q*8];
      #pragma unroll
      for (int nt=0;nt<2;nt++)
        acc[nt] = __builtin_amdgcn_mfma_f32_16x16x32_bf16(a, bcur[nt], acc[nt], 0,0,0);
      bcur[0] = bnx[0]; bcur[1] = bnx[1];
    }
  }
  const int nn = n0 + rw;
  #pragma unroll
  for (int nt=0;nt<2;nt++){
    int co = co0 + cw*32 + nt*16 + l16;
    float s=0.f, qq=0.f;
    #pragma unroll
    for (int e=0;e<4;e++){ float xv = acc[nt][e]; s += xv; qq += xv*xv; }
    s  += __shfl_xor(s,16,64);  s  += __shfl_xor(s,32,64);
    qq += __shfl_xor(qq,16,64); qq += __shfl_xor(qq,32,64);
    float mu = s*(1.f/16.f), var = qq*(1.f/16.f) - mu*mu;
    float gmv = rsqrtf(var+EPSF)*g[co];
    float btv = be[co] - mu*gmv;
    #pragma unroll
    for (int e=0;e<4;e++){
      int px = q*4 + e;
      float vv = lrelu(acc[nt][e]*gmv+btv);
      feat [(nn<<12) + (co<<4) + px] = vv;
      featb[(nn<<12) + (co<<4) + px] = cvt_bf16(vv);
    }
  }
}

// ---- gemmM MFMA: Cp[z] = featb(256x4096 bf16) @ T(4096x3200 fp32->bf16), ksplit 8x512.
__global__ __launch_bounds__(256) void gemmM_k(const unsigned short* __restrict__ A,
                                               const float* __restrict__ T,
                                               float* __restrict__ Cp){
  const int t = threadIdx.x;
  const int n0 = blockIdx.x<<7, b0 = blockIdx.y<<7, k0 = blockIdx.z<<9;
  const int w = t>>6, lane = t&63, q = lane>>4, l16 = lane&15;
  const int rw = w&1, cw = w>>1;
  __shared__ unsigned short Asm[128*40];
  __shared__ unsigned short Bsm[128*40];
  floatx4 acc[4][4];
  #pragma unroll
  for (int mt=0;mt<4;mt++)
    #pragma unroll
    for (int nt=0;nt<4;nt++) acc[mt][nt] = (floatx4){0.f,0.f,0.f,0.f};
  for (int kk=0; kk<512; kk+=32){
    if (kk) __syncthreads();
    #pragma unroll
    for (int m=0;m<2;m++){
      int idx = t + (m<<8);
      int row = idx>>2, seg = idx&3;
      uint4 v = *(const uint4*)&A[(b0+row)*4096 + k0 + kk + (seg<<3)];
      *(uint4*)&Asm[row*40 + (seg<<3)] = v;
    }
    #pragma unroll
    for (int m=0;m<4;m++){
      int idx = t + (m<<8);
      int kr = idx>>5, ns = (idx&31)<<2;
      float4 v = *(const float4*)&T[(k0+kk+kr)*3200 + n0 + ns];
      Bsm[(ns+0)*40 + kr] = cvt_bf16(v.x);
      Bsm[(ns+1)*40 + kr] = cvt_bf16(v.y);
      Bsm[(ns+2)*40 + kr] = cvt_bf16(v.z);
      Bsm[(ns+3)*40 + kr] = cvt_bf16(v.w);
    }
    __syncthreads();
    short8v af[4], bfr[4];
    #pragma unroll
    for (int mt=0;mt<4;mt++) af[mt] = *(const short8v*)&Asm[((rw<<6)+(mt<<4)+l16)*40 + (q<<3)];
    #pragma unroll
    for (int nt=0;nt<4;nt++) bfr[nt] = *(const short8v*)&Bsm[((cw<<6)+(nt<<4)+l16)*40 + (q<<3)];
    #pragma unroll
    for (int mt=0;mt<4;mt++)
      #pragma unroll
      for (int nt=0;nt<4;nt++)
        acc[mt][nt] = __builtin_amdgcn_mfma_f32_16x16x32_bf16(af[mt], bfr[nt], acc[mt][nt], 0,0,0);
  }
  float* C = Cp + blockIdx.z * 819200;
  #pragma unroll
  for (int mt=0;mt<4;mt++)
    #pragma unroll
    for (int nt=0;nt<4;nt++)
      #pragma unroll
      for (int e=0;e<4;e++){
        int row = b0 + (rw<<6) + (mt<<4) + (q<<2) + e;
        int col = n0 + (cw<<6) + (nt<<4) + l16;
        C[row*3200 + col] = acc[mt][nt][e];
      }
}

// reduce 8 partials -> Mh f16, rows padded [i][o][52]
__global__ __launch_bounds__(256) void reduceM_k(const float* __restrict__ Cp, __half* __restrict__ Mh){
  int idx = blockIdx.x*256 + threadIdx.x;
  if (idx >= 851968) return;
  int i = idx / 3328, r = idx - i*3328;
  int o = r / 52, k = r - o*52;
  float v = 0.f;
  if (k < 50){
    int src = i*3200 + o*50 + k;
    #pragma unroll
    for (int s = 0; s < 8; s++) v += Cp[s*819200 + src];
  }
  Mh[idx] = __float2half(v);
}

// ---- pairwise via packed f16
__global__ __launch_bounds__(256) void pair_k(const __half* __restrict__ Mh,
                                              float* __restrict__ ob, unsigned short* __restrict__ obb){
  const int j = blockIdx.x, t = threadIdx.x;
  __shared__ __half2 Mj[1664];
  __shared__ float red[256];
  for (int k=t; k<1664; k+=256) Mj[k] = *(const __half2*)&Mh[j*3328 + (k<<1)];
  __syncthreads();
  const int o = t & 63, ss = t >> 6;
  const __half2* mjp = &Mj[o*26];
  float sum = 0.f;
  for (int i = ss<<6; i < (ss<<6)+64; i++){
    const __half2* mip = (const __half2*)&Mh[i*3328 + o*52];
    __half2 acch = __float2half2_rn(0.f);
    #pragma unroll
    for (int k2=0;k2<26;k2++){
      __half2 d = __hsub2(mip[k2], mjp[k2]);
      acch = __hadd2(acch, __habs2(d));
    }
    float dsum = __low2float(acch) + __high2float(acch);
    sum += __expf(-dsum);
  }
  red[(o<<2)+ss] = sum;
  __syncthreads();
  if (t < 64){
    float v = red[t<<2] + red[(t<<2)+1] + red[(t<<2)+2] + red[(t<<2)+3] - 1.0f;
    ob[(j<<6)+t] = v;
    obb[(j<<6)+t] = cvt_bf16(v);
  }
}

// ---- gemmFC MFMA: yp[z] = mb(256x4160 bf16) @ fcw(1000x4160 fp32->bf16)^T, ksplit 13x320.
__global__ __launch_bounds__(256) void gemmFC_k(const unsigned short* __restrict__ featb,
                                                const unsigned short* __restrict__ obb,
                                                const float* __restrict__ W, float* __restrict__ Cp){
  const int t = threadIdx.x;
  const int o0 = blockIdx.x<<7, b0 = blockIdx.y<<7, k0 = blockIdx.z*320;
  const int w = t>>6, lane = t&63, q = lane>>4, l16 = lane&15;
  const int rw = w&1, cw = w>>1;
  __shared__ unsigned short Asm[128*40];
  __shared__ unsigned short Bsm[128*40];
  floatx4 acc[4][4];
  #pragma unroll
  for (int mt=0;mt<4;mt++)
    #pragma unroll
    for (int nt=0;nt<4;nt++) acc[mt][nt] = (floatx4){0.f,0.f,0.f,0.f};
  for (int kk=0; kk<320; kk+=32){
    if (kk) __syncthreads();
    #pragma unroll
    for (int m=0;m<2;m++){
      int idx = t + (m<<8);
      int row = idx>>2, seg = idx&3;
      int i = k0 + kk + (seg<<3);
      uint4 v;
      if (i < 4096) v = *(const uint4*)&featb[(b0+row)*4096 + i];
      else          v = *(const uint4*)&obb[(b0+row)*64 + (i-4096)];
      *(uint4*)&Asm[row*40 + (seg<<3)] = v;
    }
    #pragma unroll
    for (int m=0;m<4;m++){
      int idx = t + (m<<8);
      int orow = idx>>3, seg = idx&7;
      int oo = o0 + orow;
      float4 v = {0,0,0,0};
      if (oo < 1000) v = *(const float4*)&W[oo*4160 + k0 + kk + (seg<<2)];
      unsigned short h[4] = {cvt_bf16(v.x), cvt_bf16(v.y), cvt_bf16(v.z), cvt_bf16(v.w)};
      *(uint2*)&Bsm[orow*40 + (seg<<2)] = *(uint2*)h;
    }
    __syncthreads();
    short8v af[4], bfr[4];
    #pragma unroll
    for (int mt=0;mt<4;mt++) af[mt] = *(const short8v*)&Asm[((rw<<6)+(mt<<4)+l16)*40 + (q<<3)];
    #pragma unroll
    for (int nt=0;nt<4;nt++) bfr[nt] = *(const short8v*)&Bsm[((cw<<6)+(nt<<4)+l16)*40 + (q<<3)];
    #pragma unroll
    for (int mt=0;mt<4;mt++)
      #pragma unroll
      for (int nt=0;nt<4;nt++)
        acc[mt][nt] = __builtin_amdgcn_mfma_f32_16x16x32_bf16(af[mt], bfr[nt], acc[mt][nt], 0,0,0);
  }
  float* C = Cp + blockIdx.z * 256000;
  #pragma unroll
  for (int mt=0;mt<4;mt++)
    #pragma unroll
    for (int nt=0;nt<4;nt++)
      #pragma unroll
      for (int e=0;e<4;e++){
        int row = b0 + (rw<<6) + (mt<<4) + (q<<2) + e;
        int col = o0 + (cw<<6) + (nt<<4) + l16;
        if (col < 1000) C[row*1000 + col] = acc[mt][nt][e];
      }
}

__global__ __launch_bounds__(256) void reduceY_k(const float* __restrict__ Cp, const float* __restrict__ bias,
                                                 float* __restrict__ y){
  int idx = blockIdx.x * 256 + threadIdx.x;
  if (idx >= 256000) return;
  int o = idx % 1000;
  float r = bias[o];
  #pragma unroll
  for (int s = 0; s < 13; s++) r += Cp[s*256000 + idx];
  y[idx] = r;
}

extern "C" void kernel_launch(void* const* d_in, const int* in_sizes, int n_in,
                              void* d_out, int out_size, void* d_ws, size_t ws_size,
                              hipStream_t stream){
  const float* x   = (const float*)d_in[0];
  const float* w1  = (const float*)d_in[1];
  const float* g1  = (const float*)d_in[3];
  const float* be1 = (const float*)d_in[4];
  const float* w2  = (const float*)d_in[5];
  const float* g2  = (const float*)d_in[7];
  const float* be2 = (const float*)d_in[8];
  const float* w3  = (const float*)d_in[9];
  const float* g3  = (const float*)d_in[11];
  const float* be3 = (const float*)d_in[12];
  const float* w4  = (const float*)d_in[13];
  const float* g4  = (const float*)d_in[15];
  const float* be4 = (const float*)d_in[16];
  const float* T   = (const float*)d_in[17];
  const float* fcw = (const float*)d_in[18];
  const float* fcb = (const float*)d_in[19];
  float* out = (float*)d_out;
  float* ws  = (float*)d_ws;

  // workspace (float units)
  unsigned short* f1raw = (unsigned short*)ws;               // 8,388,608 fl
  unsigned short* f2    = (unsigned short*)(ws + 8388608);   // 4,194,304 fl
  unsigned short* f3    = (unsigned short*)(ws + 12582912);  // 2,097,152 fl
  unsigned short* featb = (unsigned short*)(ws + 14680064);  //   524,288 fl
  unsigned short* wb1   = (unsigned short*)(ws + 15204352);  //     4,096 fl
  unsigned short* wb2   = (unsigned short*)(ws + 15208448);  //   102,400 fl
  unsigned short* wb3   = (unsigned short*)(ws + 15310848);  //   409,600 fl
  unsigned short* wb4   = (unsigned short*)(ws + 15720448);  //   294,912 fl
  float* S1    = ws + 16015360;                              //    16,384
  float* Q1    = ws + 16031744;                              //    16,384
  float* S2    = ws + 16048128;                              //    32,768
  float* Q2    = ws + 16080896;                              //    32,768  (end 16,113,664)
  float* Mp    = ws + 16113664;                              // 6,553,600
  __half* Mh   = (__half*)(ws + 22667264);                   //   425,984 fl
  float* obuf  = ws + 23093248;                              //    16,384
  unsigned short* obb = (unsigned short*)(ws + 23109632);    //     8,192 fl
  float* yp    = ws + 23117824;                              // 3,328,000 (end 26,445,824 fl)
  float* feat  = out;
  float* y     = out + 1048576;

  prep_k<<<dim3(6720), 256, 0, stream>>>(w1, w2, w3, w4, wb1, wb2, wb3, wb4, S1);

  conv1_k<<<dim3(512),     256, 0, stream>>>(x, wb1, S1, Q1, f1raw);
  conv2_k<<<dim3(512),     256, 0, stream>>>(f1raw, wb2, S1, Q1, g1, be1, S2, Q2, f2);
  conv3_k<<<dim3(256, 2),  256, 0, stream>>>(f2, wb3, S2, Q2, g2, be2, g3, be3, f3);
  conv4_k<<<dim3(128, 4),  256, 0, stream>>>(f3, wb4, g4, be4, feat, featb);

  gemmM_k  <<<dim3(25, 2, 8),  256, 0, stream>>>(featb, T, Mp);
  reduceM_k<<<dim3(3328),      256, 0, stream>>>(Mp, Mh);
  pair_k   <<<dim3(256),       256, 0, stream>>>(Mh, obuf, obb);
  gemmFC_k <<<dim3(8, 2, 13),  256, 0, stream>>>(featb, obb, fcw, yp);
  reduceY_k<<<dim3(1000),      256, 0, stream>>>(yp, fcb, y);
}